// Round 2
// baseline (403.626 us; speedup 1.0000x reference)
//
#include <hip/hip_runtime.h>
#include <hip/hip_bf16.h>

// x[32768,256] f32, W[256,256], b[256], emb[1024,256]
// d_out: quant[32768*256] | indices[32768] (as float) | loss[1]
//
// Pipeline:
//   k_ee      : ee[n] = sum emb[n]^2 (+ zeroes the compaction counter)
//   k_pack    : emb -> bf16, packed in MFMA-fragment order for k_screen's
//               global_load_lds streaming.
//   k_proj    : z = x @ W^T + b via 3-way-split bf16 MFMA (err ~3e-7)
//   k_screen  : bf16 MFMA distance screen -> idx (+4096 flag if top-2 gap
//               < B_S). Fold/argmin/flag logic is the EXACT round-3 code.
//   k_compact : global ballot+atomic compaction of flagged token ids into
//               a worklist (order arbitrary; per-token result independent
//               of order -> deterministic output).
//   k_rescore2: exact fp32 re-argmin over the global worklist, grid-stride
//               balanced. emb tiles staged in XOR-swizzled LDS with
//               one-tile-ahead register prefetch. Per-(code,token) dot is
//               the EXACT validated chain (c ascending, x/y/z/w), zz the
//               EXACT validated shuffle pattern, s = fma(-2,dot,fl(zz+ee)),
//               global lexicographic (value,index) min -> bit-identical
//               results to the harness-proven k_rescore.
//   k_gather  : quant = emb[idx] (in-place over z), loss partials
//   k_loss    : 1.25 * sum / (T*D)
//
// Numerics: reference dist = fl(fl(zz+ee[n]) - 2*dot) quantized to ulp(~256)
// ~3e-5. Screen score error sigma ~2.7e-5; B_S = 5e-4 >> 8*sigma + 2 ulp, so
// unflagged tokens have a guaranteed-unique exact argmin; flagged tokens get
// the full exact scan — the round-2/3 validated formula.
#define TT 32768
#define DD 256
#define KK 1024
#define B_S 5e-4f

typedef __attribute__((ext_vector_type(8)))  short bf16x8;
typedef __attribute__((ext_vector_type(4)))  short bf16x4s;
typedef __attribute__((ext_vector_type(16))) float f32x16;

static inline __device__ short f2bf(float v) {
    __hip_bfloat16 h = __float2bfloat16(v);
    return __builtin_bit_cast(short, h);
}
static inline __device__ float bf2f(short s) {
    __hip_bfloat16 h = __builtin_bit_cast(__hip_bfloat16, s);
    return __bfloat162float(h);
}

// async global->LDS, 16B per lane. LDS dest must be wave-uniform.
static inline __device__ void gload16(const void* g, void* l) {
    __builtin_amdgcn_global_load_lds(
        (const __attribute__((address_space(1))) void*)g,
        (__attribute__((address_space(3))) void*)l,
        16, 0, 0);
}

// ---------------------------------------------------------------------------
__global__ void k_ee(const float* __restrict__ emb, float* __restrict__ ee,
                     int* __restrict__ g_nf) {
    if (blockIdx.x == 0 && threadIdx.x == 0) g_nf[0] = 0;
    int n = blockIdx.x * 256 + threadIdx.x;
    if (n >= KK) return;
    const float4* r = (const float4*)(emb + (size_t)n * DD);
    float s = 0.f;
#pragma unroll
    for (int i = 0; i < DD / 4; ++i) {
        float4 v = r[i];
        s += v.x * v.x + v.y * v.y + v.z * v.z + v.w * v.w;
    }
    ee[n] = s;
}

// ---------------------------------------------------------------------------
// Pack emb as bf16 in MFMA-fragment order. 16B unit u (0..32767):
//   lane=u&63, ks=(u>>6)&1, nb=(u>>7)&3, kbi=(u>>9)&7, nc=(u>>12)&7
//   holds emb[nc*128 + nb*32 + (lane&31)][kbi*32 + ks*16 + (lane>>5)*8 .. +7]
__global__ void k_pack(const float* __restrict__ emb, short* __restrict__ pemb) {
    int u = blockIdx.x * 256 + threadIdx.x;
    int lane = u & 63;
    int ks  = (u >> 6) & 1, nb = (u >> 7) & 3;
    int kbi = (u >> 9) & 7, nc = (u >> 12) & 7;
    int n = nc * 128 + nb * 32 + (lane & 31);
    int k = kbi * 32 + ks * 16 + (lane >> 5) * 8;
    const float* src = emb + (size_t)n * DD + k;
    float4 v0 = *(const float4*)(src);
    float4 v1 = *(const float4*)(src + 4);
    bf16x8 hb = { f2bf(v0.x), f2bf(v0.y), f2bf(v0.z), f2bf(v0.w),
                  f2bf(v1.x), f2bf(v1.y), f2bf(v1.z), f2bf(v1.w) };
    *(bf16x8*)(pemb + (size_t)u * 8) = hb;
}

// ---------------------------------------------------------------------------
// z = x @ W^T + b via 3-way split bf16 MFMA. 64 tokens x 256 outs per block.
#define PW 40   // bf16 row stride for 32-k tiles (80 B: 16B-aligned)

__launch_bounds__(256, 2)
__global__ void k_proj(const float* __restrict__ x, const float* __restrict__ W,
                       const float* __restrict__ bias, float* __restrict__ z) {
    __shared__ __align__(16) short Ax[3][64 * PW];    // 15 KB
    __shared__ __align__(16) short Bw[3][256 * PW];   // 60 KB
    const int tid = threadIdx.x;
    const int w = tid >> 6, lane = tid & 63;
    const int l31 = lane & 31, h = lane >> 5;
    const int t0 = blockIdx.x * 64;
    const int wt = (w & 1) * 32;        // wave token offset
    const int wc = (w >> 1) * 128;      // wave col offset

    f32x16 acc[4];
#pragma unroll
    for (int cb = 0; cb < 4; ++cb)
#pragma unroll
        for (int r = 0; r < 16; ++r) acc[cb][r] = 0.f;

    for (int kb = 0; kb < DD; kb += 32) {
        __syncthreads();
        // x tile 64x32 -> 3-way split
#pragma unroll
        for (int j = 0; j < 2; ++j) {
            int idx = j * 256 + tid, row = idx >> 3, c4 = idx & 7;
            float4 v = *(const float4*)(x + (size_t)(t0 + row) * DD + kb + c4 * 4);
            float e[4] = {v.x, v.y, v.z, v.w};
            bf16x4s s1, s2, s3;
#pragma unroll
            for (int q = 0; q < 4; ++q) {
                short h1 = f2bf(e[q]); float r1 = e[q] - bf2f(h1);
                short h2 = f2bf(r1);   float r2 = r1 - bf2f(h2);
                short h3 = f2bf(r2);
                s1[q] = h1; s2[q] = h2; s3[q] = h3;
            }
            int a = row * PW + c4 * 4;
            *(bf16x4s*)&Ax[0][a] = s1; *(bf16x4s*)&Ax[1][a] = s2; *(bf16x4s*)&Ax[2][a] = s3;
        }
        // W tile 256x32 -> 3-way split
#pragma unroll
        for (int j = 0; j < 8; ++j) {
            int idx = j * 256 + tid, row = idx >> 3, c4 = idx & 7;
            float4 v = *(const float4*)(W + (size_t)row * DD + kb + c4 * 4);
            float e[4] = {v.x, v.y, v.z, v.w};
            bf16x4s s1, s2, s3;
#pragma unroll
            for (int q = 0; q < 4; ++q) {
                short h1 = f2bf(e[q]); float r1 = e[q] - bf2f(h1);
                short h2 = f2bf(r1);   float r2 = r1 - bf2f(h2);
                short h3 = f2bf(r2);
                s1[q] = h1; s2[q] = h2; s3[q] = h3;
            }
            int a = row * PW + c4 * 4;
            *(bf16x4s*)&Bw[0][a] = s1; *(bf16x4s*)&Bw[1][a] = s2; *(bf16x4s*)&Bw[2][a] = s3;
        }
        __syncthreads();
#pragma unroll
        for (int ks = 0; ks < 2; ++ks) {
            int ao = (wt + l31) * PW + ks * 16 + h * 8;
            bf16x8 a1 = *(bf16x8*)&Ax[0][ao];
            bf16x8 a2 = *(bf16x8*)&Ax[1][ao];
            bf16x8 a3 = *(bf16x8*)&Ax[2][ao];
#pragma unroll
            for (int cb = 0; cb < 4; ++cb) {
                int bo = (wc + cb * 32 + l31) * PW + ks * 16 + h * 8;
                bf16x8 b1 = *(bf16x8*)&Bw[0][bo];
                bf16x8 b2 = *(bf16x8*)&Bw[1][bo];
                bf16x8 b3 = *(bf16x8*)&Bw[2][bo];
                // small terms first for accumulation accuracy
                acc[cb] = __builtin_amdgcn_mfma_f32_32x32x16_bf16(a1, b3, acc[cb], 0, 0, 0);
                acc[cb] = __builtin_amdgcn_mfma_f32_32x32x16_bf16(a2, b2, acc[cb], 0, 0, 0);
                acc[cb] = __builtin_amdgcn_mfma_f32_32x32x16_bf16(a3, b1, acc[cb], 0, 0, 0);
                acc[cb] = __builtin_amdgcn_mfma_f32_32x32x16_bf16(a1, b2, acc[cb], 0, 0, 0);
                acc[cb] = __builtin_amdgcn_mfma_f32_32x32x16_bf16(a2, b1, acc[cb], 0, 0, 0);
                acc[cb] = __builtin_amdgcn_mfma_f32_32x32x16_bf16(a1, b1, acc[cb], 0, 0, 0);
            }
        }
    }
    // epilogue: C/D layout col=lane&31, row=(r&3)+8*(r>>2)+4*(lane>>5)
#pragma unroll
    for (int cb = 0; cb < 4; ++cb) {
        int col = wc + cb * 32 + l31;
        float bc = bias[col];
#pragma unroll
        for (int r = 0; r < 16; ++r) {
            int row = (r & 3) + 8 * (r >> 2) + 4 * h;
            z[(size_t)(t0 + wt + row) * DD + col] = acc[cb][r] + bc;
        }
    }
}

// ---------------------------------------------------------------------------
// bf16 MFMA screening. Fold/argmin/flag = EXACT round-3 code. B path:
// prepacked bf16 emb streamed via global_load_lds, double-buffered 8KB tiles,
// one barrier per tile, lane-linear (conflict-free) fragment reads.
#define SW 264   // A_s row stride (bf16 elems)

__launch_bounds__(256, 2)
__global__ void k_screen(const float* __restrict__ z, const short* __restrict__ pemb,
                         const float* __restrict__ ee_g, float* __restrict__ out_idx) {
    __shared__ __align__(16) short A_s[64 * SW];       // 33 KB
    __shared__ __align__(16) short B_s[2][8 * 512];    // 2 x 8 KB, linear tiles
    __shared__ float ee_s[1024];
    __shared__ float zzs[64];
    __shared__ float r_bv[64]; __shared__ int r_bi[64]; __shared__ float r_sv[64];

    const int tid = threadIdx.x;
    const int w = tid >> 6, lane = tid & 63;
    const int l31 = lane & 31, h = lane >> 5;
    const int t0 = blockIdx.x * 64;
    const int wr = (w >> 1) * 32, wc = (w & 1) * 64;

#pragma unroll
    for (int i = 0; i < 4; ++i) ee_s[i * 256 + tid] = ee_g[i * 256 + tid];

    // A init: z tile -> bf16 LDS (full K=256 resident) + exact fp32 zz sums
#pragma unroll
    for (int i = 0; i < 16; ++i) {
        int tl = i * 4 + w;
        float4 v = *(const float4*)(z + (size_t)(t0 + tl) * DD + lane * 4);
        float sq = v.x * v.x + v.y * v.y + v.z * v.z + v.w * v.w;
#pragma unroll
        for (int o = 32; o; o >>= 1) sq += __shfl_xor(sq, o);
        if (lane == 0) zzs[tl] = sq;
        bf16x4s hb = {f2bf(v.x), f2bf(v.y), f2bf(v.z), f2bf(v.w)};
        *(bf16x4s*)&A_s[tl * SW + lane * 4] = hb;
    }

    // prologue: issue tile 0 into buffer 0 (wave w loads chunks 2w, 2w+1)
#pragma unroll
    for (int i = 0; i < 2; ++i) {
        gload16(pemb + ((w * 2 + i) * 64 + lane) * 8, &B_s[0][(w * 2 + i) * 512]);
    }

    float bestv[16], secv[16]; int besti[16];
#pragma unroll
    for (int r = 0; r < 16; ++r) { bestv[r] = 1e30f; secv[r] = 1e30f; besti[r] = 0; }

    f32x16 acc0, acc1;
    for (int t = 0; t < 64; ++t) {
        const int nc = t >> 3, kbi = t & 7, buf = t & 1;
        if (kbi == 0) {
#pragma unroll
            for (int r = 0; r < 16; ++r) { acc0[r] = 0.f; acc1[r] = 0.f; }
        }
        asm volatile("s_waitcnt vmcnt(0)" ::: "memory");
        __syncthreads();
        if (t < 63) {
            const short* gt = pemb + (size_t)(t + 1) * 4096;
#pragma unroll
            for (int i = 0; i < 2; ++i) {
                gload16(gt + ((w * 2 + i) * 64 + lane) * 8,
                        &B_s[buf ^ 1][(w * 2 + i) * 512]);
            }
        }
#pragma unroll
        for (int ks = 0; ks < 2; ++ks) {
            bf16x8 a  = *(bf16x8*)&A_s[(wr + l31) * SW + kbi * 32 + ks * 16 + h * 8];
            bf16x8 b0 = *(bf16x8*)&B_s[buf][(((wc >> 5) + 0) * 2 + ks) * 512 + lane * 8];
            bf16x8 b1 = *(bf16x8*)&B_s[buf][(((wc >> 5) + 1) * 2 + ks) * 512 + lane * 8];
            acc0 = __builtin_amdgcn_mfma_f32_32x32x16_bf16(a, b0, acc0, 0, 0, 0);
            acc1 = __builtin_amdgcn_mfma_f32_32x32x16_bf16(a, b1, acc1, 0, 0, 0);
        }
        if (kbi == 7) {
#pragma unroll
            for (int j = 0; j < 2; ++j) {
                int n = nc * 128 + wc + j * 32 + l31;
                float en = ee_s[n];
#pragma unroll
                for (int r = 0; r < 16; ++r) {
                    int row = (r & 3) + 8 * (r >> 2) + 4 * h;
                    float u = zzs[wr + row] + en;
                    float d = (j == 0) ? acc0[r] : acc1[r];
                    float s = fmaf(-2.f, d, u);
                    if (s < bestv[r])      { secv[r] = bestv[r]; bestv[r] = s; besti[r] = n; }
                    else if (s < secv[r])  { secv[r] = s; }
                }
            }
        }
    }

    // cross-lane reduce within each 32-lane half (cols)
#pragma unroll
    for (int o = 1; o < 32; o <<= 1) {
#pragma unroll
        for (int r = 0; r < 16; ++r) {
            float ov = __shfl_xor(bestv[r], o);
            int   oi = __shfl_xor(besti[r], o);
            float os = __shfl_xor(secv[r], o);
            float mx = fmaxf(bestv[r], ov);
            secv[r] = fminf(fminf(secv[r], os), mx);
            if (ov < bestv[r] || (ov == bestv[r] && oi < besti[r])) { bestv[r] = ov; besti[r] = oi; }
        }
    }
    // combine the two col-parity waves per row block via LDS
    if ((w & 1) == 0 && l31 == 0) {
#pragma unroll
        for (int r = 0; r < 16; ++r) {
            int tr = wr + (r & 3) + 8 * (r >> 2) + 4 * h;
            r_bv[tr] = bestv[r]; r_bi[tr] = besti[r]; r_sv[tr] = secv[r];
        }
    }
    __syncthreads();
    if ((w & 1) == 1 && l31 == 0) {
#pragma unroll
        for (int r = 0; r < 16; ++r) {
            int tr = wr + (r & 3) + 8 * (r >> 2) + 4 * h;
            float lv = r_bv[tr]; int li = r_bi[tr]; float ls = r_sv[tr];
            float mx = fmaxf(lv, bestv[r]);
            float ns = fminf(fminf(ls, secv[r]), mx);
            float nv; int ni;
            if (bestv[r] < lv || (bestv[r] == lv && besti[r] < li)) { nv = bestv[r]; ni = besti[r]; }
            else { nv = lv; ni = li; }
            r_bv[tr] = nv; r_bi[tr] = ni; r_sv[tr] = ns;
        }
    }
    __syncthreads();
    if (tid < 64) {
        float bv = r_bv[tid], sv = r_sv[tid];
        int bi = r_bi[tid];
        float flag = ((sv - bv) < B_S) ? 4096.0f : 0.0f;
        out_idx[t0 + tid] = (float)bi + flag;
    }
}

// ---------------------------------------------------------------------------
// Compact flagged token ids into a global worklist. Order across blocks is
// arbitrary (atomicAdd), but each token appears exactly once and its rescore
// result is independent of list position -> deterministic outputs.
__global__ void k_compact(const float* __restrict__ out_idx, int* __restrict__ g_nf,
                          int* __restrict__ g_list) {
    __shared__ int wbase[4];
    __shared__ int bbase;
    const int tid = threadIdx.x;
    const int t = blockIdx.x * 256 + tid;
    const int wid = tid >> 6, lane = tid & 63;
    bool fl = out_idx[t] >= 4096.0f;
    unsigned long long m = __ballot(fl);
    if (lane == 0) wbase[wid] = __popcll(m);
    __syncthreads();
    if (tid == 0) {
        int s = 0;
#pragma unroll
        for (int i = 0; i < 4; ++i) { int c = wbase[i]; wbase[i] = s; s += c; }
        bbase = atomicAdd(g_nf, s);
    }
    __syncthreads();
    if (fl) {
        int rank = __popcll(m & ((1ull << lane) - 1ull));
        g_list[bbase + wbase[wid] + rank] = t;
    }
}

// ---------------------------------------------------------------------------
// Exact fp32 re-argmin over the global worklist. 16 tokens/batch, grid-stride.
// emb staged per 32-row tile into XOR-swizzled LDS (conflict-free row reads),
// with register prefetch of tile t+1 issued before tile t's dot (hides L2
// latency). Each thread owns (row r = tid&31, tokens q0/q1) -> 2 independent
// exact FMA chains. All arithmetic chains are bit-identical to the
// harness-proven k_rescore (see header comment).
#define RB 16    // tokens per batch
#define TR 32    // emb rows per tile

__launch_bounds__(256, 2)
__global__ void k_rescore2(const float* __restrict__ z, const float* __restrict__ emb,
                           const float* __restrict__ ee_g, const int* __restrict__ g_nf,
                           const int* __restrict__ g_list, float* __restrict__ out_idx) {
    __shared__ float zrows[RB][256];                 // 16 KB
    __shared__ float zz8[RB];
    __shared__ __align__(16) float et[TR * 256];     // 32 KB, swizzled chunks
    __shared__ int toks[RB];
    const int tid = threadIdx.x;
    const int w = tid >> 6, lane = tid & 63;
    const int r  = tid & 31;          // emb row within tile
    const int g  = tid >> 5;          // token-pair group 0..7
    const int q0 = g * 2, q1 = q0 + 1;
    const int nf = g_nf[0];

    for (int base = blockIdx.x * RB; base < nf; base += gridDim.x * RB) {
        if (tid < RB) toks[tid] = (base + tid < nf) ? g_list[base + tid] : -1;
        __syncthreads();
        // stage z rows (pad slots -> zeros: no stale-LDS reads)
#pragma unroll
        for (int qq = 0; qq < RB; ++qq) {
            int tok = toks[qq];
            zrows[qq][tid] = (tok >= 0) ? z[(size_t)tok * DD + tid] : 0.f;
        }
        // prefetch emb tile 0 into registers (independent of LDS state)
        float4 pf[8];
#pragma unroll
        for (int j = 0; j < 8; ++j) {
            int idx = j * 256 + tid, rr = idx >> 6, cc = idx & 63;
            pf[j] = *(const float4*)(emb + (size_t)rr * DD + cc * 4);
        }
        __syncthreads();
        // zz — EXACT validated per-row arithmetic (lane partials k,k+64,..,
        // then 32..1 xor-shuffle)
        for (int qq = w; qq < RB; qq += 4) {
            float s = 0.f;
#pragma unroll
            for (int k = 0; k < 4; ++k) { float vv = zrows[qq][lane + 64 * k]; s += vv * vv; }
#pragma unroll
            for (int o = 32; o; o >>= 1) s += __shfl_xor(s, o);
            if (lane == 0) zz8[qq] = s;
        }
        __syncthreads();   // zz ready; et free

        float bv0 = 1e30f, bv1 = 1e30f; int bi0 = 0, bi1 = 0;
        for (int tile = 0; tile < 32; ++tile) {
            // write prefetched tile into swizzled LDS
#pragma unroll
            for (int j = 0; j < 8; ++j) {
                int idx = j * 256 + tid, rr = idx >> 6, cc = idx & 63;
                *(float4*)&et[rr * 256 + ((cc ^ (rr & 7)) << 2)] = pf[j];
            }
            __syncthreads();
            // issue next tile's loads (latency hides under the dot below)
            if (tile < 31) {
                const float* src = emb + (size_t)(tile + 1) * TR * DD;
#pragma unroll
                for (int j = 0; j < 8; ++j) {
                    int idx = j * 256 + tid, rr = idx >> 6, cc = idx & 63;
                    pf[j] = *(const float4*)(src + (size_t)rr * DD + cc * 4);
                }
            }
            // EXACT dot chains: c ascending, x,y,z,w order, one chain per
            // (row, token); two independent chains per thread for ILP.
            float d0 = 0.f, d1 = 0.f;
            const float* er = &et[r * 256];
            const float* za = &zrows[q0][0];
            const float* zb = &zrows[q1][0];
#pragma unroll 8
            for (int c = 0; c < 64; ++c) {
                float4 e  = *(const float4*)&er[((c ^ (r & 7)) << 2)];
                float4 z0 = *(const float4*)&za[c * 4];
                float4 z1 = *(const float4*)&zb[c * 4];
                d0 = fmaf(e.x, z0.x, d0); d1 = fmaf(e.x, z1.x, d1);
                d0 = fmaf(e.y, z0.y, d0); d1 = fmaf(e.y, z1.y, d1);
                d0 = fmaf(e.z, z0.z, d0); d1 = fmaf(e.z, z1.z, d1);
                d0 = fmaf(e.w, z0.w, d0); d1 = fmaf(e.w, z1.w, d1);
            }
            int n = tile * TR + r;
            float en = ee_g[n];
            float u0 = zz8[q0] + en;          // fl(zz+ee[n])
            float s0 = fmaf(-2.f, d0, u0);    // fl(u - 2*dot)
            if (s0 < bv0) { bv0 = s0; bi0 = n; }   // n ascending per thread
            float u1 = zz8[q1] + en;
            float s1 = fmaf(-2.f, d1, u1);
            if (s1 < bv1) { bv1 = s1; bi1 = n; }
            __syncthreads();   // all dots done before next tile overwrite
        }
        // reduce over the 32 threads (one half-wave) sharing each token:
        // global lexicographic (value, index) first-min — identical to the
        // validated reduction semantics.
#pragma unroll
        for (int o = 1; o < 32; o <<= 1) {
            float ov0 = __shfl_xor(bv0, o); int oi0 = __shfl_xor(bi0, o);
            if (ov0 < bv0 || (ov0 == bv0 && oi0 < bi0)) { bv0 = ov0; bi0 = oi0; }
            float ov1 = __shfl_xor(bv1, o); int oi1 = __shfl_xor(bi1, o);
            if (ov1 < bv1 || (ov1 == bv1 && oi1 < bi1)) { bv1 = ov1; bi1 = oi1; }
        }
        if (r == 0) {
            int t0k = toks[q0];
            if (t0k >= 0) out_idx[t0k] = (float)bi0;
            int t1k = toks[q1];
            if (t1k >= 0) out_idx[t1k] = (float)bi1;
        }
        __syncthreads();   // protect toks/zrows before next batch
    }
}

// ---------------------------------------------------------------------------
__global__ void k_gather(float* __restrict__ zq, const float* __restrict__ emb,
                         const float* __restrict__ out_idx, float* __restrict__ partial) {
    __shared__ float red[4];
    const int tid = threadIdx.x;
    const int t0 = blockIdx.x * 128;
    const int tl = tid >> 1, part = tid & 1;
    int widx = (int)out_idx[t0 + tl];
    widx = min(max(widx, 0), KK - 1);
    const float* erow = emb + (size_t)widx * DD;
    float* qrow = zq + (size_t)(t0 + tl) * DD;
    float lsum = 0.f;
#pragma unroll
    for (int k = 0; k < 32; ++k) {
        int f = part + 2 * k;
        float4 e  = *(const float4*)(erow + f * 4);
        float4 zv = *(const float4*)(qrow + f * 4);
        float dx = e.x - zv.x, dy = e.y - zv.y, dz = e.z - zv.z, dw = e.w - zv.w;
        lsum += dx * dx + dy * dy + dz * dz + dw * dw;
        *(float4*)(qrow + f * 4) = e;
    }
#pragma unroll
    for (int off = 32; off; off >>= 1) lsum += __shfl_down(lsum, off);
    if ((tid & 63) == 0) red[tid >> 6] = lsum;
    __syncthreads();
    if (tid == 0) partial[blockIdx.x] = red[0] + red[1] + red[2] + red[3];
}

// ---------------------------------------------------------------------------
__global__ void k_loss(const float* __restrict__ partial, float* __restrict__ out_loss) {
    __shared__ float red[4];
    int tid = threadIdx.x;
    float s = partial[tid];
#pragma unroll
    for (int off = 32; off; off >>= 1) s += __shfl_down(s, off);
    if ((tid & 63) == 0) red[tid >> 6] = s;
    __syncthreads();
    if (tid == 0)
        out_loss[0] = (red[0] + red[1] + red[2] + red[3]) * (1.25f / 8388608.0f);
}

// ---------------------------------------------------------------------------
extern "C" void kernel_launch(void* const* d_in, const int* in_sizes, int n_in,
                              void* d_out, int out_size, void* d_ws, size_t ws_size,
                              hipStream_t stream) {
    const float* x   = (const float*)d_in[0];
    const float* W   = (const float*)d_in[1];
    const float* b   = (const float*)d_in[2];
    const float* emb = (const float*)d_in[3];

    float* out   = (float*)d_out;
    float* quant = out;                          // holds z, then quant
    float* oidx  = out + (size_t)TT * DD;
    float* oloss = oidx + TT;

    float* ee      = (float*)d_ws;               // 1024 f
    float* partial = ee + KK;                    // 256 f
    short* pemb    = (short*)(partial + 256);    // 262144 bf16 (512 KB)
    int*   g_nf    = (int*)(pemb + 262144);      // 1 int
    int*   g_list  = g_nf + 1;                   // up to 32768 ints

    k_ee      <<<KK / 256, 256, 0, stream>>>(emb, ee, g_nf);
    k_pack    <<<128,      256, 0, stream>>>(emb, pemb);
    k_proj    <<<TT / 64,  256, 0, stream>>>(x, W, b, quant);
    k_screen  <<<TT / 64,  256, 0, stream>>>(quant, pemb, ee, oidx);
    k_compact <<<TT / 256, 256, 0, stream>>>(oidx, g_nf, g_list);
    k_rescore2<<<256,      256, 0, stream>>>(quant, emb, ee, g_nf, g_list, oidx);
    k_gather  <<<TT / 128, 256, 0, stream>>>(quant, emb, oidx, partial);
    k_loss    <<<1,        256, 0, stream>>>(partial, oloss);
}

// Round 3
// 351.736 us; speedup vs baseline: 1.1475x; 1.1475x over previous
//
#include <hip/hip_runtime.h>
#include <hip/hip_bf16.h>

// x[32768,256] f32, W[256,256], b[256], emb[1024,256]
// d_out: quant[32768*256] | indices[32768] (as float) | loss[1]
//
// Pipeline:
//   k_ee      : ee[n] = sum emb[n]^2 (+ zeroes the compaction counter)
//   k_pack    : emb -> bf16, packed in MFMA-fragment order.
//   k_proj    : z = x @ W^T + b via 3-way-split bf16 MFMA (err ~3e-7)
//   k_screen  : bf16 MFMA distance screen -> idx (+4096 flag if top-2 gap
//               < B_S). Fold/argmin/flag logic is the EXACT round-3 code.
//               B fragments now stream straight into REGISTERS (4-deep ring,
//               zero barriers in the main loop; A_s is read-only after init).
//               MFMA operand values and per-acc order unchanged -> scores
//               bit-identical to the harness-proven version.
//   k_compact : ballot+atomic compaction of flagged token ids (order
//               arbitrary; per-token result order-independent).
//   k_rescore3: exact fp32 re-argmin, 4 codes x 4 tokens register-blocked.
//               Wave owns 4 tokens (z reads broadcast); e-tile in LDS with
//               even-spread XOR swizzle. Dot chain (c ascending, x/y/z/w),
//               zz shuffle pattern, s = fma(-2,dot,fl(zz+ee)), ascending-n
//               first-min + lexicographic (v,i) reduce: bit-identical to the
//               harness-proven k_rescore semantics.
//   k_gather  : quant = emb[idx] (in-place over z), loss partials
//   k_loss    : 1.25 * sum / (T*D)
//
// Numerics: reference dist = fl(fl(zz+ee[n]) - 2*dot) quantized to ulp(~256)
// ~3e-5. Screen score error sigma ~2.7e-5; B_S = 5e-4 >> 8*sigma + 2 ulp, so
// unflagged tokens have a guaranteed-unique exact argmin; flagged tokens get
// the full exact scan — the round-2/3 validated formula.
#define TT 32768
#define DD 256
#define KK 1024
#define B_S 5e-4f

typedef __attribute__((ext_vector_type(8)))  short bf16x8;
typedef __attribute__((ext_vector_type(4)))  short bf16x4s;
typedef __attribute__((ext_vector_type(16))) float f32x16;

static inline __device__ short f2bf(float v) {
    __hip_bfloat16 h = __float2bfloat16(v);
    return __builtin_bit_cast(short, h);
}
static inline __device__ float bf2f(short s) {
    __hip_bfloat16 h = __builtin_bit_cast(__hip_bfloat16, s);
    return __bfloat162float(h);
}

// ---------------------------------------------------------------------------
__global__ void k_ee(const float* __restrict__ emb, float* __restrict__ ee,
                     int* __restrict__ g_nf) {
    if (blockIdx.x == 0 && threadIdx.x == 0) g_nf[0] = 0;
    int n = blockIdx.x * 256 + threadIdx.x;
    if (n >= KK) return;
    const float4* r = (const float4*)(emb + (size_t)n * DD);
    float s = 0.f;
#pragma unroll
    for (int i = 0; i < DD / 4; ++i) {
        float4 v = r[i];
        s += v.x * v.x + v.y * v.y + v.z * v.z + v.w * v.w;
    }
    ee[n] = s;
}

// ---------------------------------------------------------------------------
// Pack emb as bf16 in MFMA-fragment order. 16B unit u (0..32767):
//   lane=u&63, ks=(u>>6)&1, nb=(u>>7)&3, kbi=(u>>9)&7, nc=(u>>12)&7
//   holds emb[nc*128 + nb*32 + (lane&31)][kbi*32 + ks*16 + (lane>>5)*8 .. +7]
__global__ void k_pack(const float* __restrict__ emb, short* __restrict__ pemb) {
    int u = blockIdx.x * 256 + threadIdx.x;
    int lane = u & 63;
    int ks  = (u >> 6) & 1, nb = (u >> 7) & 3;
    int kbi = (u >> 9) & 7, nc = (u >> 12) & 7;
    int n = nc * 128 + nb * 32 + (lane & 31);
    int k = kbi * 32 + ks * 16 + (lane >> 5) * 8;
    const float* src = emb + (size_t)n * DD + k;
    float4 v0 = *(const float4*)(src);
    float4 v1 = *(const float4*)(src + 4);
    bf16x8 hb = { f2bf(v0.x), f2bf(v0.y), f2bf(v0.z), f2bf(v0.w),
                  f2bf(v1.x), f2bf(v1.y), f2bf(v1.z), f2bf(v1.w) };
    *(bf16x8*)(pemb + (size_t)u * 8) = hb;
}

// ---------------------------------------------------------------------------
// z = x @ W^T + b via 3-way split bf16 MFMA. 64 tokens x 256 outs per block.
#define PW 40   // bf16 row stride for 32-k tiles (80 B: 16B-aligned)

__launch_bounds__(256, 2)
__global__ void k_proj(const float* __restrict__ x, const float* __restrict__ W,
                       const float* __restrict__ bias, float* __restrict__ z) {
    __shared__ __align__(16) short Ax[3][64 * PW];    // 15 KB
    __shared__ __align__(16) short Bw[3][256 * PW];   // 60 KB
    const int tid = threadIdx.x;
    const int w = tid >> 6, lane = tid & 63;
    const int l31 = lane & 31, h = lane >> 5;
    const int t0 = blockIdx.x * 64;
    const int wt = (w & 1) * 32;        // wave token offset
    const int wc = (w >> 1) * 128;      // wave col offset

    f32x16 acc[4];
#pragma unroll
    for (int cb = 0; cb < 4; ++cb)
#pragma unroll
        for (int r = 0; r < 16; ++r) acc[cb][r] = 0.f;

    for (int kb = 0; kb < DD; kb += 32) {
        __syncthreads();
        // x tile 64x32 -> 3-way split
#pragma unroll
        for (int j = 0; j < 2; ++j) {
            int idx = j * 256 + tid, row = idx >> 3, c4 = idx & 7;
            float4 v = *(const float4*)(x + (size_t)(t0 + row) * DD + kb + c4 * 4);
            float e[4] = {v.x, v.y, v.z, v.w};
            bf16x4s s1, s2, s3;
#pragma unroll
            for (int q = 0; q < 4; ++q) {
                short h1 = f2bf(e[q]); float r1 = e[q] - bf2f(h1);
                short h2 = f2bf(r1);   float r2 = r1 - bf2f(h2);
                short h3 = f2bf(r2);
                s1[q] = h1; s2[q] = h2; s3[q] = h3;
            }
            int a = row * PW + c4 * 4;
            *(bf16x4s*)&Ax[0][a] = s1; *(bf16x4s*)&Ax[1][a] = s2; *(bf16x4s*)&Ax[2][a] = s3;
        }
        // W tile 256x32 -> 3-way split
#pragma unroll
        for (int j = 0; j < 8; ++j) {
            int idx = j * 256 + tid, row = idx >> 3, c4 = idx & 7;
            float4 v = *(const float4*)(W + (size_t)row * DD + kb + c4 * 4);
            float e[4] = {v.x, v.y, v.z, v.w};
            bf16x4s s1, s2, s3;
#pragma unroll
            for (int q = 0; q < 4; ++q) {
                short h1 = f2bf(e[q]); float r1 = e[q] - bf2f(h1);
                short h2 = f2bf(r1);   float r2 = r1 - bf2f(h2);
                short h3 = f2bf(r2);
                s1[q] = h1; s2[q] = h2; s3[q] = h3;
            }
            int a = row * PW + c4 * 4;
            *(bf16x4s*)&Bw[0][a] = s1; *(bf16x4s*)&Bw[1][a] = s2; *(bf16x4s*)&Bw[2][a] = s3;
        }
        __syncthreads();
#pragma unroll
        for (int ks = 0; ks < 2; ++ks) {
            int ao = (wt + l31) * PW + ks * 16 + h * 8;
            bf16x8 a1 = *(bf16x8*)&Ax[0][ao];
            bf16x8 a2 = *(bf16x8*)&Ax[1][ao];
            bf16x8 a3 = *(bf16x8*)&Ax[2][ao];
#pragma unroll
            for (int cb = 0; cb < 4; ++cb) {
                int bo = (wc + cb * 32 + l31) * PW + ks * 16 + h * 8;
                bf16x8 b1 = *(bf16x8*)&Bw[0][bo];
                bf16x8 b2 = *(bf16x8*)&Bw[1][bo];
                bf16x8 b3 = *(bf16x8*)&Bw[2][bo];
                // small terms first for accumulation accuracy
                acc[cb] = __builtin_amdgcn_mfma_f32_32x32x16_bf16(a1, b3, acc[cb], 0, 0, 0);
                acc[cb] = __builtin_amdgcn_mfma_f32_32x32x16_bf16(a2, b2, acc[cb], 0, 0, 0);
                acc[cb] = __builtin_amdgcn_mfma_f32_32x32x16_bf16(a3, b1, acc[cb], 0, 0, 0);
                acc[cb] = __builtin_amdgcn_mfma_f32_32x32x16_bf16(a1, b2, acc[cb], 0, 0, 0);
                acc[cb] = __builtin_amdgcn_mfma_f32_32x32x16_bf16(a2, b1, acc[cb], 0, 0, 0);
                acc[cb] = __builtin_amdgcn_mfma_f32_32x32x16_bf16(a1, b1, acc[cb], 0, 0, 0);
            }
        }
    }
    // epilogue: C/D layout col=lane&31, row=(r&3)+8*(r>>2)+4*(lane>>5)
#pragma unroll
    for (int cb = 0; cb < 4; ++cb) {
        int col = wc + cb * 32 + l31;
        float bc = bias[col];
#pragma unroll
        for (int r = 0; r < 16; ++r) {
            int row = (r & 3) + 8 * (r >> 2) + 4 * h;
            z[(size_t)(t0 + wt + row) * DD + col] = acc[cb][r] + bc;
        }
    }
}

// ---------------------------------------------------------------------------
// bf16 MFMA screening. Fold/argmin/flag = EXACT round-3 code. B fragments
// loaded straight into registers from the prepacked buffer: 4-deep ring,
// perfectly coalesced 16B/lane loads, ZERO barriers in the main loop
// (A_s is read-only after the single init barrier). Same MFMA values and
// per-accumulator order as the validated kernel -> bit-identical scores.
#define SW 264   // A_s row stride (bf16 elems)

__launch_bounds__(256, 2)
__global__ void k_screen(const float* __restrict__ z, const short* __restrict__ pemb,
                         const float* __restrict__ ee_g, float* __restrict__ out_idx) {
    __shared__ __align__(16) short A_s[64 * SW];       // 33 KB
    __shared__ float ee_s[1024];
    __shared__ float zzs[64];
    __shared__ float r_bv[64]; __shared__ int r_bi[64]; __shared__ float r_sv[64];

    const int tid = threadIdx.x;
    const int w = tid >> 6, lane = tid & 63;
    const int l31 = lane & 31, h = lane >> 5;
    const int t0 = blockIdx.x * 64;
    const int wr = (w >> 1) * 32, wc = (w & 1) * 64;

#pragma unroll
    for (int i = 0; i < 4; ++i) ee_s[i * 256 + tid] = ee_g[i * 256 + tid];

    // A init: z tile -> bf16 LDS (full K=256 resident) + exact fp32 zz sums
#pragma unroll
    for (int i = 0; i < 16; ++i) {
        int tl = i * 4 + w;
        float4 v = *(const float4*)(z + (size_t)(t0 + tl) * DD + lane * 4);
        float sq = v.x * v.x + v.y * v.y + v.z * v.z + v.w * v.w;
#pragma unroll
        for (int o = 32; o; o >>= 1) sq += __shfl_xor(sq, o);
        if (lane == 0) zzs[tl] = sq;
        bf16x4s hb = {f2bf(v.x), f2bf(v.y), f2bf(v.z), f2bf(v.w)};
        *(bf16x4s*)&A_s[tl * SW + lane * 4] = hb;
    }
    __syncthreads();   // A_s, zzs, ee_s ready — the ONLY barrier before epilogue

    // per-wave B fragment units within a tile (16B unit = chunk*64 + lane)
    const int u00 = ((((w & 1) * 2 + 0) * 2 + 0) * 64 + lane) * 8;  // b0 ks0
    const int u01 = ((((w & 1) * 2 + 0) * 2 + 1) * 64 + lane) * 8;  // b0 ks1
    const int u10 = ((((w & 1) * 2 + 1) * 2 + 0) * 64 + lane) * 8;  // b1 ks0
    const int u11 = ((((w & 1) * 2 + 1) * 2 + 1) * 64 + lane) * 8;  // b1 ks1

    // 4-deep register ring of B fragments
    bf16x8 B00[4], B01[4], B10[4], B11[4];
#pragma unroll
    for (int s = 0; s < 4; ++s) {
        const short* gt = pemb + (size_t)s * 4096;
        B00[s] = *(const bf16x8*)(gt + u00);
        B01[s] = *(const bf16x8*)(gt + u01);
        B10[s] = *(const bf16x8*)(gt + u10);
        B11[s] = *(const bf16x8*)(gt + u11);
    }

    float bestv[16], secv[16]; int besti[16];
#pragma unroll
    for (int r = 0; r < 16; ++r) { bestv[r] = 1e30f; secv[r] = 1e30f; besti[r] = 0; }

    f32x16 acc0, acc1;
    for (int tq = 0; tq < 16; ++tq) {
#pragma unroll
        for (int s = 0; s < 4; ++s) {
            const int t = tq * 4 + s;
            const int nc = t >> 3, kbi = t & 7;
            if (kbi == 0) {
#pragma unroll
                for (int r = 0; r < 16; ++r) { acc0[r] = 0.f; acc1[r] = 0.f; }
            }
            // A fragments for this (kbi); ks0 then ks1 per acc (validated order)
            bf16x8 a0 = *(bf16x8*)&A_s[(wr + l31) * SW + kbi * 32 + 0 * 16 + h * 8];
            bf16x8 a1 = *(bf16x8*)&A_s[(wr + l31) * SW + kbi * 32 + 1 * 16 + h * 8];
            acc0 = __builtin_amdgcn_mfma_f32_32x32x16_bf16(a0, B00[s], acc0, 0, 0, 0);
            acc1 = __builtin_amdgcn_mfma_f32_32x32x16_bf16(a0, B10[s], acc1, 0, 0, 0);
            acc0 = __builtin_amdgcn_mfma_f32_32x32x16_bf16(a1, B01[s], acc0, 0, 0, 0);
            acc1 = __builtin_amdgcn_mfma_f32_32x32x16_bf16(a1, B11[s], acc1, 0, 0, 0);
            // refill this slot with tile t+4 (clamped; tail reloads are unused)
            {
                const int tn = (t + 4 > 63) ? 63 : t + 4;
                const short* gt = pemb + (size_t)tn * 4096;
                B00[s] = *(const bf16x8*)(gt + u00);
                B01[s] = *(const bf16x8*)(gt + u01);
                B10[s] = *(const bf16x8*)(gt + u10);
                B11[s] = *(const bf16x8*)(gt + u11);
            }
            // fold: s = fl(fl(zz+ee) - 2*dot), track top-2 values + best index
            if (kbi == 7) {
#pragma unroll
                for (int j = 0; j < 2; ++j) {
                    int n = nc * 128 + wc + j * 32 + l31;
                    float en = ee_s[n];
#pragma unroll
                    for (int r = 0; r < 16; ++r) {
                        int row = (r & 3) + 8 * (r >> 2) + 4 * h;
                        float u = zzs[wr + row] + en;
                        float d = (j == 0) ? acc0[r] : acc1[r];
                        float sc = fmaf(-2.f, d, u);
                        if (sc < bestv[r])      { secv[r] = bestv[r]; bestv[r] = sc; besti[r] = n; }
                        else if (sc < secv[r])  { secv[r] = sc; }
                    }
                }
            }
        }
    }

    // cross-lane reduce within each 32-lane half (cols)
#pragma unroll
    for (int o = 1; o < 32; o <<= 1) {
#pragma unroll
        for (int r = 0; r < 16; ++r) {
            float ov = __shfl_xor(bestv[r], o);
            int   oi = __shfl_xor(besti[r], o);
            float os = __shfl_xor(secv[r], o);
            float mx = fmaxf(bestv[r], ov);
            secv[r] = fminf(fminf(secv[r], os), mx);
            if (ov < bestv[r] || (ov == bestv[r] && oi < besti[r])) { bestv[r] = ov; besti[r] = oi; }
        }
    }
    // combine the two col-parity waves per row block via LDS
    if ((w & 1) == 0 && l31 == 0) {
#pragma unroll
        for (int r = 0; r < 16; ++r) {
            int tr = wr + (r & 3) + 8 * (r >> 2) + 4 * h;
            r_bv[tr] = bestv[r]; r_bi[tr] = besti[r]; r_sv[tr] = secv[r];
        }
    }
    __syncthreads();
    if ((w & 1) == 1 && l31 == 0) {
#pragma unroll
        for (int r = 0; r < 16; ++r) {
            int tr = wr + (r & 3) + 8 * (r >> 2) + 4 * h;
            float lv = r_bv[tr]; int li = r_bi[tr]; float ls = r_sv[tr];
            float mx = fmaxf(lv, bestv[r]);
            float ns = fminf(fminf(ls, secv[r]), mx);
            float nv; int ni;
            if (bestv[r] < lv || (bestv[r] == lv && besti[r] < li)) { nv = bestv[r]; ni = besti[r]; }
            else { nv = lv; ni = li; }
            r_bv[tr] = nv; r_bi[tr] = ni; r_sv[tr] = ns;
        }
    }
    __syncthreads();
    if (tid < 64) {
        float bv = r_bv[tid], sv = r_sv[tid];
        int bi = r_bi[tid];
        float flag = ((sv - bv) < B_S) ? 4096.0f : 0.0f;
        out_idx[t0 + tid] = (float)bi + flag;
    }
}

// ---------------------------------------------------------------------------
// Compact flagged token ids into a global worklist (order-independent result).
__global__ void k_compact(const float* __restrict__ out_idx, int* __restrict__ g_nf,
                          int* __restrict__ g_list) {
    __shared__ int wbase[4];
    __shared__ int bbase;
    const int tid = threadIdx.x;
    const int t = blockIdx.x * 256 + tid;
    const int wid = tid >> 6, lane = tid & 63;
    bool fl = out_idx[t] >= 4096.0f;
    unsigned long long m = __ballot(fl);
    if (lane == 0) wbase[wid] = __popcll(m);
    __syncthreads();
    if (tid == 0) {
        int s = 0;
#pragma unroll
        for (int i = 0; i < 4; ++i) { int c = wbase[i]; wbase[i] = s; s += c; }
        bbase = atomicAdd(g_nf, s);
    }
    __syncthreads();
    if (fl) {
        int rank = __popcll(m & ((1ull << lane) - 1ull));
        g_list[bbase + wbase[wid] + rank] = t;
    }
}

// ---------------------------------------------------------------------------
// Exact fp32 re-argmin. 16 tokens/batch grid-stride. Register blocking:
// thread = 4 codes (n = p*256 + lane*4 + jc) x 4 tokens (wave-owned ->
// broadcast z reads). e-tile 256 codes x 32 floats in LDS, XOR swizzle
// slot = kk ^ ((row>>2)&7) -> exactly-even bank spread for the strided
// (row = lane*4+jc) reads. All chains bit-identical to validated k_rescore.
#define RB 16    // tokens per batch

__launch_bounds__(256, 2)
__global__ void k_rescore3(const float* __restrict__ z, const float* __restrict__ emb,
                           const float* __restrict__ ee_g, const int* __restrict__ g_nf,
                           const int* __restrict__ g_list, float* __restrict__ out_idx) {
    __shared__ float zrows[RB][256];                 // 16 KB
    __shared__ float zz8[RB];
    __shared__ __align__(16) float et[256 * 32];     // 32 KB (256 codes x 32 f)
    __shared__ int toks[RB];
    const int tid = threadIdx.x;
    const int w = tid >> 6, lane = tid & 63;
    const int nf = g_nf[0];

    // staging index split (fixed per thread): 8 float4 units, unit j covers
    // row rj = (j*256+tid)>>3, float4-slot kj = (j*256+tid)&7 of the e-tile.
    for (int base = blockIdx.x * RB; base < nf; base += gridDim.x * RB) {
        __syncthreads();   // previous batch fully done (toks/zrows reuse)
        if (tid < RB) toks[tid] = (base + tid < nf) ? g_list[base + tid] : -1;
        __syncthreads();
#pragma unroll
        for (int qq = 0; qq < RB; ++qq) {
            int tok = toks[qq];
            zrows[qq][tid] = (tok >= 0) ? z[(size_t)tok * DD + tid] : 0.f;
        }
        __syncthreads();
        // zz — EXACT validated per-row arithmetic
        for (int qq = w; qq < RB; qq += 4) {
            float s = 0.f;
#pragma unroll
            for (int k = 0; k < 4; ++k) { float vv = zrows[qq][lane + 64 * k]; s += vv * vv; }
#pragma unroll
            for (int o = 32; o; o >>= 1) s += __shfl_xor(s, o);
            if (lane == 0) zz8[qq] = s;
        }
        // prefetch phase 0 (pass 0, kc 0)
        float4 pf[8];
#pragma unroll
        for (int j = 0; j < 8; ++j) {
            int idx = j * 256 + tid, rj = idx >> 3, kj = idx & 7;
            pf[j] = *(const float4*)(emb + (size_t)rj * DD + kj * 4);
        }
        __syncthreads();   // zz8 ready

        float bv[4]; int bi[4];
#pragma unroll
        for (int jt = 0; jt < 4; ++jt) { bv[jt] = 1e30f; bi[jt] = 0; }
        float d[4][4];

        for (int ph = 0; ph < 32; ++ph) {
            const int p = ph >> 3, kc = ph & 7;
            if (kc == 0) {
#pragma unroll
                for (int jc = 0; jc < 4; ++jc)
#pragma unroll
                    for (int jt = 0; jt < 4; ++jt) d[jc][jt] = 0.f;
            }
            // write prefetched chunk into swizzled LDS
#pragma unroll
            for (int j = 0; j < 8; ++j) {
                int idx = j * 256 + tid, rj = idx >> 3, kj = idx & 7;
                *(float4*)&et[rj * 32 + ((kj ^ ((rj >> 2) & 7)) << 2)] = pf[j];
            }
            __syncthreads();
            // prefetch next chunk (latency hides under the dot below)
            if (ph < 31) {
                const int pn = (ph + 1) >> 3, kcn = (ph + 1) & 7;
#pragma unroll
                for (int j = 0; j < 8; ++j) {
                    int idx = j * 256 + tid, rj = idx >> 3, kj = idx & 7;
                    pf[j] = *(const float4*)(emb + (size_t)(pn * 256 + rj) * DD + kcn * 32 + kj * 4);
                }
            }
            // EXACT dot chains: c = kc*8+kk ascending, x/y/z/w order per chain
#pragma unroll
            for (int kk = 0; kk < 8; ++kk) {
                float4 zq[4];
#pragma unroll
                for (int jt = 0; jt < 4; ++jt)
                    zq[jt] = *(const float4*)&zrows[w * 4 + jt][kc * 32 + kk * 4];  // broadcast
#pragma unroll
                for (int jc = 0; jc < 4; ++jc) {
                    int rr = lane * 4 + jc;
                    float4 e = *(const float4*)&et[rr * 32 + ((kk ^ ((rr >> 2) & 7)) << 2)];
#pragma unroll
                    for (int jt = 0; jt < 4; ++jt) {
                        d[jc][jt] = fmaf(e.x, zq[jt].x, d[jc][jt]);
                        d[jc][jt] = fmaf(e.y, zq[jt].y, d[jc][jt]);
                        d[jc][jt] = fmaf(e.z, zq[jt].z, d[jc][jt]);
                        d[jc][jt] = fmaf(e.w, zq[jt].w, d[jc][jt]);
                    }
                }
            }
            // end of pass: fold 4 codes x 4 tokens (n ascending per token)
            if (kc == 7) {
#pragma unroll
                for (int jt = 0; jt < 4; ++jt) {
#pragma unroll
                    for (int jc = 0; jc < 4; ++jc) {
                        int n = p * 256 + lane * 4 + jc;
                        float en = ee_g[n];
                        float u = zz8[w * 4 + jt] + en;        // fl(zz+ee[n])
                        float s = fmaf(-2.f, d[jc][jt], u);    // fl(u - 2*dot)
                        if (s < bv[jt]) { bv[jt] = s; bi[jt] = n; }
                    }
                }
            }
            __syncthreads();   // et reads done before next overwrite
        }
        // per-token reduce over the owning wave's 64 lanes (disjoint codes):
        // lexicographic (value, index) first-min — validated semantics.
#pragma unroll
        for (int jt = 0; jt < 4; ++jt) {
            float v = bv[jt]; int i = bi[jt];
#pragma unroll
            for (int o = 1; o < 64; o <<= 1) {
                float ov = __shfl_xor(v, o); int oi = __shfl_xor(i, o);
                if (ov < v || (ov == v && oi < i)) { v = ov; i = oi; }
            }
            if (lane == 0) {
                int tk = toks[w * 4 + jt];
                if (tk >= 0) out_idx[tk] = (float)i;
            }
        }
    }
}

// ---------------------------------------------------------------------------
__global__ void k_gather(float* __restrict__ zq, const float* __restrict__ emb,
                         const float* __restrict__ out_idx, float* __restrict__ partial) {
    __shared__ float red[4];
    const int tid = threadIdx.x;
    const int t0 = blockIdx.x * 128;
    const int tl = tid >> 1, part = tid & 1;
    int widx = (int)out_idx[t0 + tl];
    widx = min(max(widx, 0), KK - 1);
    const float* erow = emb + (size_t)widx * DD;
    float* qrow = zq + (size_t)(t0 + tl) * DD;
    float lsum = 0.f;
#pragma unroll
    for (int k = 0; k < 32; ++k) {
        int f = part + 2 * k;
        float4 e  = *(const float4*)(erow + f * 4);
        float4 zv = *(const float4*)(qrow + f * 4);
        float dx = e.x - zv.x, dy = e.y - zv.y, dz = e.z - zv.z, dw = e.w - zv.w;
        lsum += dx * dx + dy * dy + dz * dz + dw * dw;
        *(float4*)(qrow + f * 4) = e;
    }
#pragma unroll
    for (int off = 32; off; off >>= 1) lsum += __shfl_down(lsum, off);
    if ((tid & 63) == 0) red[tid >> 6] = lsum;
    __syncthreads();
    if (tid == 0) partial[blockIdx.x] = red[0] + red[1] + red[2] + red[3];
}

// ---------------------------------------------------------------------------
__global__ void k_loss(const float* __restrict__ partial, float* __restrict__ out_loss) {
    __shared__ float red[4];
    int tid = threadIdx.x;
    float s = partial[tid];
#pragma unroll
    for (int off = 32; off; off >>= 1) s += __shfl_down(s, off);
    if ((tid & 63) == 0) red[tid >> 6] = s;
    __syncthreads();
    if (tid == 0)
        out_loss[0] = (red[0] + red[1] + red[2] + red[3]) * (1.25f / 8388608.0f);
}

// ---------------------------------------------------------------------------
extern "C" void kernel_launch(void* const* d_in, const int* in_sizes, int n_in,
                              void* d_out, int out_size, void* d_ws, size_t ws_size,
                              hipStream_t stream) {
    const float* x   = (const float*)d_in[0];
    const float* W   = (const float*)d_in[1];
    const float* b   = (const float*)d_in[2];
    const float* emb = (const float*)d_in[3];

    float* out   = (float*)d_out;
    float* quant = out;                          // holds z, then quant
    float* oidx  = out + (size_t)TT * DD;
    float* oloss = oidx + TT;

    float* ee      = (float*)d_ws;               // 1024 f
    float* partial = ee + KK;                    // 256 f
    short* pemb    = (short*)(partial + 256);    // 262144 bf16 (512 KB)
    int*   g_nf    = (int*)(pemb + 262144);      // 1 int
    int*   g_list  = g_nf + 1;                   // up to 32768 ints

    k_ee      <<<KK / 256, 256, 0, stream>>>(emb, ee, g_nf);
    k_pack    <<<128,      256, 0, stream>>>(emb, pemb);
    k_proj    <<<TT / 64,  256, 0, stream>>>(x, W, b, quant);
    k_screen  <<<TT / 64,  256, 0, stream>>>(quant, pemb, ee, oidx);
    k_compact <<<TT / 256, 256, 0, stream>>>(oidx, g_nf, g_list);
    k_rescore3<<<256,      256, 0, stream>>>(quant, emb, ee, g_nf, g_list, oidx);
    k_gather  <<<TT / 128, 256, 0, stream>>>(quant, emb, oidx, partial);
    k_loss    <<<1,        256, 0, stream>>>(partial, oloss);
}

// Round 4
// 346.473 us; speedup vs baseline: 1.1650x; 1.0152x over previous
//
#include <hip/hip_runtime.h>
#include <hip/hip_bf16.h>

// x[32768,256] f32, W[256,256], b[256], emb[1024,256]
// d_out: quant[32768*256] | indices[32768] (as float) | loss[1]
//
// Pipeline:
//   k_ee      : ee[n] = sum emb[n]^2 (+ zeroes the compaction counter)
//   k_pack    : emb -> bf16 packed in MFMA-fragment order (for k_screen) AND
//               emb -> fp32 transposed embP4[k4][n] (bit-exact copy, for
//               k_rescoreT's coalesced per-code loads).
//   k_proj    : z = x @ W^T + b via 3-way-split bf16 MFMA (err ~3e-7)
//   k_screen  : bf16 MFMA distance screen -> idx (+4096 flag if top-2 gap
//               < B_S). Fold/argmin/flag logic is the EXACT round-3 code;
//               B fragments stream straight into registers (4-deep ring,
//               zero barriers in the main loop). Scores bit-identical.
//   k_compact : ballot+atomic compaction of flagged token ids (order
//               arbitrary; per-token result order-independent).
//   k_rescoreT: exact fp32 re-argmin over the worklist. Thread owns code
//               n = p*256+tid (p=0..3); e loads coalesced from embP4 (L2),
//               z broadcast from LDS; NO LDS writes / barriers in the
//               k-loop. Dot chain (k ascending, x/y/z/w), zz shuffle,
//               s = fma(-2,dot,fl(zz+ee)), ascending-n first-min and
//               lexicographic (v,i) reduce: copied verbatim from the
//               harness-proven k_rescore -> bit-identical results.
//   k_gather  : quant = emb[idx] (in-place over z), loss partials
//   k_loss    : 1.25 * sum / (T*D)
//
// Numerics: reference dist = fl(fl(zz+ee[n]) - 2*dot) quantized to ulp(~256)
// ~3e-5. Screen score error sigma ~2.7e-5; B_S = 5e-4 >> 8*sigma + 2 ulp, so
// unflagged tokens have a guaranteed-unique exact argmin; flagged tokens get
// the full exact scan — the round-2/3 validated formula.
#define TT 32768
#define DD 256
#define KK 1024
#define B_S 5e-4f

typedef __attribute__((ext_vector_type(8)))  short bf16x8;
typedef __attribute__((ext_vector_type(4)))  short bf16x4s;
typedef __attribute__((ext_vector_type(16))) float f32x16;

static inline __device__ short f2bf(float v) {
    __hip_bfloat16 h = __float2bfloat16(v);
    return __builtin_bit_cast(short, h);
}
static inline __device__ float bf2f(short s) {
    __hip_bfloat16 h = __builtin_bit_cast(__hip_bfloat16, s);
    return __bfloat162float(h);
}

// ---------------------------------------------------------------------------
__global__ void k_ee(const float* __restrict__ emb, float* __restrict__ ee,
                     int* __restrict__ g_nf) {
    if (blockIdx.x == 0 && threadIdx.x == 0) g_nf[0] = 0;
    int n = blockIdx.x * 256 + threadIdx.x;
    if (n >= KK) return;
    const float4* r = (const float4*)(emb + (size_t)n * DD);
    float s = 0.f;
#pragma unroll
    for (int i = 0; i < DD / 4; ++i) {
        float4 v = r[i];
        s += v.x * v.x + v.y * v.y + v.z * v.z + v.w * v.w;
    }
    ee[n] = s;
}

// ---------------------------------------------------------------------------
// Pack emb as bf16 in MFMA-fragment order (pemb) and as fp32 transposed
// float4 blocks (embP4[k4*1024 + n] = emb[n][k4*4 .. +3], bit-exact).
// 16B unit u (0..32767):
//   lane=u&63, ks=(u>>6)&1, nb=(u>>7)&3, kbi=(u>>9)&7, nc=(u>>12)&7
//   holds emb[nc*128 + nb*32 + (lane&31)][kbi*32 + ks*16 + (lane>>5)*8 .. +7]
__global__ void k_pack(const float* __restrict__ emb, short* __restrict__ pemb,
                       float4* __restrict__ embP4) {
    int u = blockIdx.x * 256 + threadIdx.x;
    int lane = u & 63;
    int ks  = (u >> 6) & 1, nb = (u >> 7) & 3;
    int kbi = (u >> 9) & 7, nc = (u >> 12) & 7;
    int n = nc * 128 + nb * 32 + (lane & 31);
    int k = kbi * 32 + ks * 16 + (lane >> 5) * 8;
    const float* src = emb + (size_t)n * DD + k;
    float4 v0 = *(const float4*)(src);
    float4 v1 = *(const float4*)(src + 4);
    bf16x8 hb = { f2bf(v0.x), f2bf(v0.y), f2bf(v0.z), f2bf(v0.w),
                  f2bf(v1.x), f2bf(v1.y), f2bf(v1.z), f2bf(v1.w) };
    *(bf16x8*)(pemb + (size_t)u * 8) = hb;
    // fp32 transposed copy (bit-exact)
    embP4[(size_t)(k >> 2) * KK + n]       = v0;
    embP4[(size_t)((k >> 2) + 1) * KK + n] = v1;
}

// ---------------------------------------------------------------------------
// z = x @ W^T + b via 3-way split bf16 MFMA. 64 tokens x 256 outs per block.
#define PW 40   // bf16 row stride for 32-k tiles (80 B: 16B-aligned)

__launch_bounds__(256, 2)
__global__ void k_proj(const float* __restrict__ x, const float* __restrict__ W,
                       const float* __restrict__ bias, float* __restrict__ z) {
    __shared__ __align__(16) short Ax[3][64 * PW];    // 15 KB
    __shared__ __align__(16) short Bw[3][256 * PW];   // 60 KB
    const int tid = threadIdx.x;
    const int w = tid >> 6, lane = tid & 63;
    const int l31 = lane & 31, h = lane >> 5;
    const int t0 = blockIdx.x * 64;
    const int wt = (w & 1) * 32;        // wave token offset
    const int wc = (w >> 1) * 128;      // wave col offset

    f32x16 acc[4];
#pragma unroll
    for (int cb = 0; cb < 4; ++cb)
#pragma unroll
        for (int r = 0; r < 16; ++r) acc[cb][r] = 0.f;

    for (int kb = 0; kb < DD; kb += 32) {
        __syncthreads();
        // x tile 64x32 -> 3-way split
#pragma unroll
        for (int j = 0; j < 2; ++j) {
            int idx = j * 256 + tid, row = idx >> 3, c4 = idx & 7;
            float4 v = *(const float4*)(x + (size_t)(t0 + row) * DD + kb + c4 * 4);
            float e[4] = {v.x, v.y, v.z, v.w};
            bf16x4s s1, s2, s3;
#pragma unroll
            for (int q = 0; q < 4; ++q) {
                short h1 = f2bf(e[q]); float r1 = e[q] - bf2f(h1);
                short h2 = f2bf(r1);   float r2 = r1 - bf2f(h2);
                short h3 = f2bf(r2);
                s1[q] = h1; s2[q] = h2; s3[q] = h3;
            }
            int a = row * PW + c4 * 4;
            *(bf16x4s*)&Ax[0][a] = s1; *(bf16x4s*)&Ax[1][a] = s2; *(bf16x4s*)&Ax[2][a] = s3;
        }
        // W tile 256x32 -> 3-way split
#pragma unroll
        for (int j = 0; j < 8; ++j) {
            int idx = j * 256 + tid, row = idx >> 3, c4 = idx & 7;
            float4 v = *(const float4*)(W + (size_t)row * DD + kb + c4 * 4);
            float e[4] = {v.x, v.y, v.z, v.w};
            bf16x4s s1, s2, s3;
#pragma unroll
            for (int q = 0; q < 4; ++q) {
                short h1 = f2bf(e[q]); float r1 = e[q] - bf2f(h1);
                short h2 = f2bf(r1);   float r2 = r1 - bf2f(h2);
                short h3 = f2bf(r2);
                s1[q] = h1; s2[q] = h2; s3[q] = h3;
            }
            int a = row * PW + c4 * 4;
            *(bf16x4s*)&Bw[0][a] = s1; *(bf16x4s*)&Bw[1][a] = s2; *(bf16x4s*)&Bw[2][a] = s3;
        }
        __syncthreads();
#pragma unroll
        for (int ks = 0; ks < 2; ++ks) {
            int ao = (wt + l31) * PW + ks * 16 + h * 8;
            bf16x8 a1 = *(bf16x8*)&Ax[0][ao];
            bf16x8 a2 = *(bf16x8*)&Ax[1][ao];
            bf16x8 a3 = *(bf16x8*)&Ax[2][ao];
#pragma unroll
            for (int cb = 0; cb < 4; ++cb) {
                int bo = (wc + cb * 32 + l31) * PW + ks * 16 + h * 8;
                bf16x8 b1 = *(bf16x8*)&Bw[0][bo];
                bf16x8 b2 = *(bf16x8*)&Bw[1][bo];
                bf16x8 b3 = *(bf16x8*)&Bw[2][bo];
                // small terms first for accumulation accuracy
                acc[cb] = __builtin_amdgcn_mfma_f32_32x32x16_bf16(a1, b3, acc[cb], 0, 0, 0);
                acc[cb] = __builtin_amdgcn_mfma_f32_32x32x16_bf16(a2, b2, acc[cb], 0, 0, 0);
                acc[cb] = __builtin_amdgcn_mfma_f32_32x32x16_bf16(a3, b1, acc[cb], 0, 0, 0);
                acc[cb] = __builtin_amdgcn_mfma_f32_32x32x16_bf16(a1, b2, acc[cb], 0, 0, 0);
                acc[cb] = __builtin_amdgcn_mfma_f32_32x32x16_bf16(a2, b1, acc[cb], 0, 0, 0);
                acc[cb] = __builtin_amdgcn_mfma_f32_32x32x16_bf16(a1, b1, acc[cb], 0, 0, 0);
            }
        }
    }
    // epilogue: C/D layout col=lane&31, row=(r&3)+8*(r>>2)+4*(lane>>5)
#pragma unroll
    for (int cb = 0; cb < 4; ++cb) {
        int col = wc + cb * 32 + l31;
        float bc = bias[col];
#pragma unroll
        for (int r = 0; r < 16; ++r) {
            int row = (r & 3) + 8 * (r >> 2) + 4 * h;
            z[(size_t)(t0 + wt + row) * DD + col] = acc[cb][r] + bc;
        }
    }
}

// ---------------------------------------------------------------------------
// bf16 MFMA screening. Fold/argmin/flag = EXACT round-3 code. B fragments
// loaded straight into registers from the prepacked buffer: 4-deep ring,
// perfectly coalesced 16B/lane loads, ZERO barriers in the main loop
// (A_s is read-only after the single init barrier). Same MFMA values and
// per-accumulator order as the validated kernel -> bit-identical scores.
#define SW 264   // A_s row stride (bf16 elems)

__launch_bounds__(256, 2)
__global__ void k_screen(const float* __restrict__ z, const short* __restrict__ pemb,
                         const float* __restrict__ ee_g, float* __restrict__ out_idx) {
    __shared__ __align__(16) short A_s[64 * SW];       // 33 KB
    __shared__ float ee_s[1024];
    __shared__ float zzs[64];
    __shared__ float r_bv[64]; __shared__ int r_bi[64]; __shared__ float r_sv[64];

    const int tid = threadIdx.x;
    const int w = tid >> 6, lane = tid & 63;
    const int l31 = lane & 31, h = lane >> 5;
    const int t0 = blockIdx.x * 64;
    const int wr = (w >> 1) * 32, wc = (w & 1) * 64;

#pragma unroll
    for (int i = 0; i < 4; ++i) ee_s[i * 256 + tid] = ee_g[i * 256 + tid];

    // A init: z tile -> bf16 LDS (full K=256 resident) + exact fp32 zz sums
#pragma unroll
    for (int i = 0; i < 16; ++i) {
        int tl = i * 4 + w;
        float4 v = *(const float4*)(z + (size_t)(t0 + tl) * DD + lane * 4);
        float sq = v.x * v.x + v.y * v.y + v.z * v.z + v.w * v.w;
#pragma unroll
        for (int o = 32; o; o >>= 1) sq += __shfl_xor(sq, o);
        if (lane == 0) zzs[tl] = sq;
        bf16x4s hb = {f2bf(v.x), f2bf(v.y), f2bf(v.z), f2bf(v.w)};
        *(bf16x4s*)&A_s[tl * SW + lane * 4] = hb;
    }
    __syncthreads();   // A_s, zzs, ee_s ready — the ONLY barrier before epilogue

    // per-wave B fragment units within a tile (16B unit = chunk*64 + lane)
    const int u00 = ((((w & 1) * 2 + 0) * 2 + 0) * 64 + lane) * 8;  // b0 ks0
    const int u01 = ((((w & 1) * 2 + 0) * 2 + 1) * 64 + lane) * 8;  // b0 ks1
    const int u10 = ((((w & 1) * 2 + 1) * 2 + 0) * 64 + lane) * 8;  // b1 ks0
    const int u11 = ((((w & 1) * 2 + 1) * 2 + 1) * 64 + lane) * 8;  // b1 ks1

    // 4-deep register ring of B fragments
    bf16x8 B00[4], B01[4], B10[4], B11[4];
#pragma unroll
    for (int s = 0; s < 4; ++s) {
        const short* gt = pemb + (size_t)s * 4096;
        B00[s] = *(const bf16x8*)(gt + u00);
        B01[s] = *(const bf16x8*)(gt + u01);
        B10[s] = *(const bf16x8*)(gt + u10);
        B11[s] = *(const bf16x8*)(gt + u11);
    }

    float bestv[16], secv[16]; int besti[16];
#pragma unroll
    for (int r = 0; r < 16; ++r) { bestv[r] = 1e30f; secv[r] = 1e30f; besti[r] = 0; }

    f32x16 acc0, acc1;
    for (int tq = 0; tq < 16; ++tq) {
#pragma unroll
        for (int s = 0; s < 4; ++s) {
            const int t = tq * 4 + s;
            const int nc = t >> 3, kbi = t & 7;
            if (kbi == 0) {
#pragma unroll
                for (int r = 0; r < 16; ++r) { acc0[r] = 0.f; acc1[r] = 0.f; }
            }
            // A fragments for this (kbi); ks0 then ks1 per acc (validated order)
            bf16x8 a0 = *(bf16x8*)&A_s[(wr + l31) * SW + kbi * 32 + 0 * 16 + h * 8];
            bf16x8 a1 = *(bf16x8*)&A_s[(wr + l31) * SW + kbi * 32 + 1 * 16 + h * 8];
            acc0 = __builtin_amdgcn_mfma_f32_32x32x16_bf16(a0, B00[s], acc0, 0, 0, 0);
            acc1 = __builtin_amdgcn_mfma_f32_32x32x16_bf16(a0, B10[s], acc1, 0, 0, 0);
            acc0 = __builtin_amdgcn_mfma_f32_32x32x16_bf16(a1, B01[s], acc0, 0, 0, 0);
            acc1 = __builtin_amdgcn_mfma_f32_32x32x16_bf16(a1, B11[s], acc1, 0, 0, 0);
            // refill this slot with tile t+4 (clamped; tail reloads are unused)
            {
                const int tn = (t + 4 > 63) ? 63 : t + 4;
                const short* gt = pemb + (size_t)tn * 4096;
                B00[s] = *(const bf16x8*)(gt + u00);
                B01[s] = *(const bf16x8*)(gt + u01);
                B10[s] = *(const bf16x8*)(gt + u10);
                B11[s] = *(const bf16x8*)(gt + u11);
            }
            // fold: s = fl(fl(zz+ee) - 2*dot), track top-2 values + best index
            if (kbi == 7) {
#pragma unroll
                for (int j = 0; j < 2; ++j) {
                    int n = nc * 128 + wc + j * 32 + l31;
                    float en = ee_s[n];
#pragma unroll
                    for (int r = 0; r < 16; ++r) {
                        int row = (r & 3) + 8 * (r >> 2) + 4 * h;
                        float u = zzs[wr + row] + en;
                        float d = (j == 0) ? acc0[r] : acc1[r];
                        float sc = fmaf(-2.f, d, u);
                        if (sc < bestv[r])      { secv[r] = bestv[r]; bestv[r] = sc; besti[r] = n; }
                        else if (sc < secv[r])  { secv[r] = sc; }
                    }
                }
            }
        }
    }

    // cross-lane reduce within each 32-lane half (cols)
#pragma unroll
    for (int o = 1; o < 32; o <<= 1) {
#pragma unroll
        for (int r = 0; r < 16; ++r) {
            float ov = __shfl_xor(bestv[r], o);
            int   oi = __shfl_xor(besti[r], o);
            float os = __shfl_xor(secv[r], o);
            float mx = fmaxf(bestv[r], ov);
            secv[r] = fminf(fminf(secv[r], os), mx);
            if (ov < bestv[r] || (ov == bestv[r] && oi < besti[r])) { bestv[r] = ov; besti[r] = oi; }
        }
    }
    // combine the two col-parity waves per row block via LDS
    if ((w & 1) == 0 && l31 == 0) {
#pragma unroll
        for (int r = 0; r < 16; ++r) {
            int tr = wr + (r & 3) + 8 * (r >> 2) + 4 * h;
            r_bv[tr] = bestv[r]; r_bi[tr] = besti[r]; r_sv[tr] = secv[r];
        }
    }
    __syncthreads();
    if ((w & 1) == 1 && l31 == 0) {
#pragma unroll
        for (int r = 0; r < 16; ++r) {
            int tr = wr + (r & 3) + 8 * (r >> 2) + 4 * h;
            float lv = r_bv[tr]; int li = r_bi[tr]; float ls = r_sv[tr];
            float mx = fmaxf(lv, bestv[r]);
            float ns = fminf(fminf(ls, secv[r]), mx);
            float nv; int ni;
            if (bestv[r] < lv || (bestv[r] == lv && besti[r] < li)) { nv = bestv[r]; ni = besti[r]; }
            else { nv = lv; ni = li; }
            r_bv[tr] = nv; r_bi[tr] = ni; r_sv[tr] = ns;
        }
    }
    __syncthreads();
    if (tid < 64) {
        float bv = r_bv[tid], sv = r_sv[tid];
        int bi = r_bi[tid];
        float flag = ((sv - bv) < B_S) ? 4096.0f : 0.0f;
        out_idx[t0 + tid] = (float)bi + flag;
    }
}

// ---------------------------------------------------------------------------
// Compact flagged token ids into a global worklist (order-independent result).
__global__ void k_compact(const float* __restrict__ out_idx, int* __restrict__ g_nf,
                          int* __restrict__ g_list) {
    __shared__ int wbase[4];
    __shared__ int bbase;
    const int tid = threadIdx.x;
    const int t = blockIdx.x * 256 + tid;
    const int wid = tid >> 6, lane = tid & 63;
    bool fl = out_idx[t] >= 4096.0f;
    unsigned long long m = __ballot(fl);
    if (lane == 0) wbase[wid] = __popcll(m);
    __syncthreads();
    if (tid == 0) {
        int s = 0;
#pragma unroll
        for (int i = 0; i < 4; ++i) { int c = wbase[i]; wbase[i] = s; s += c; }
        bbase = atomicAdd(g_nf, s);
    }
    __syncthreads();
    if (fl) {
        int rank = __popcll(m & ((1ull << lane) - 1ull));
        g_list[bbase + wbase[wid] + rank] = t;
    }
}

// ---------------------------------------------------------------------------
// Exact fp32 re-argmin over the worklist, 8 tokens/batch, grid-stride.
// Thread owns code n = p*256 + tid (p = 0..3). e: coalesced float4 loads
// from the transposed pack embP4[k4*1024+n] (bit-exact emb values, L2-hot).
// z: wave-uniform broadcast float4 reads from LDS (conflict-free). The
// k-loop has NO LDS writes and NO barriers. All arithmetic chains, fold
// order, and reductions are copied verbatim from the harness-proven
// k_rescore -> bit-identical results.
#define RB 8    // tokens per batch (validated batch size)

__launch_bounds__(256, 4)
__global__ void k_rescoreT(const float* __restrict__ z, const float4* __restrict__ embP4,
                           const float* __restrict__ ee_g, const int* __restrict__ g_nf,
                           const int* __restrict__ g_list, float* __restrict__ out_idx) {
    __shared__ float zrows[RB][256];                 // 8 KB
    __shared__ float zz8[RB];
    __shared__ int   toks[RB];
    __shared__ float rv_s[RB][4]; __shared__ int ri_s[RB][4];
    const int tid = threadIdx.x;
    const int w = tid >> 6, lane = tid & 63;
    const int nf = g_nf[0];

    for (int base = blockIdx.x * RB; base < nf; base += gridDim.x * RB) {
        __syncthreads();   // previous batch fully done (zrows/toks reuse)
        if (tid < RB) toks[tid] = (base + tid < nf) ? g_list[base + tid] : -1;
        __syncthreads();
        // stage z rows (pad slots -> zeros: no stale-LDS reads)
#pragma unroll
        for (int qq = 0; qq < RB; ++qq) {
            int tok = toks[qq];
            zrows[qq][tid] = (tok >= 0) ? z[(size_t)tok * DD + tid] : 0.f;
        }
        __syncthreads();
        // zz — EXACT validated per-row arithmetic (wave w rows w, w+4)
        for (int qq = w; qq < RB; qq += 4) {
            float s = 0.f;
#pragma unroll
            for (int k = 0; k < 4; ++k) { float vv = zrows[qq][lane + 64 * k]; s += vv * vv; }
#pragma unroll
            for (int o = 32; o; o >>= 1) s += __shfl_xor(s, o);
            if (lane == 0) zz8[qq] = s;
        }
        __syncthreads();   // zz8 ready

        float bv[RB]; int bi[RB];
#pragma unroll
        for (int q = 0; q < RB; ++q) { bv[q] = 1e30f; bi[q] = 0; }

        for (int p = 0; p < 4; ++p) {
            const int n = p * 256 + tid;
            const float en = ee_g[n];
            float d[RB];
#pragma unroll
            for (int q = 0; q < RB; ++q) d[q] = 0.f;
            const float4* ep = embP4 + n;
            // EXACT dot chains: k4 ascending, x/y/z/w order per (code,token)
#pragma unroll 4
            for (int k4 = 0; k4 < 64; ++k4) {
                float4 e = ep[(size_t)k4 * KK];
#pragma unroll
                for (int q = 0; q < RB; ++q) {
                    float4 zq = *(const float4*)&zrows[q][k4 * 4];  // broadcast
                    d[q] = fmaf(e.x, zq.x, d[q]); d[q] = fmaf(e.y, zq.y, d[q]);
                    d[q] = fmaf(e.z, zq.z, d[q]); d[q] = fmaf(e.w, zq.w, d[q]);
                }
            }
#pragma unroll
            for (int q = 0; q < RB; ++q) {
                float u = zz8[q] + en;           // fl(zz+ee[n])
                float s = fmaf(-2.f, d[q], u);   // fl(u - 2*dot)
                if (s < bv[q]) { bv[q] = s; bi[q] = n; }   // ascending n/thread
            }
        }
        // per-token block reduce: lexicographic (value, index) first-min
        for (int q = 0; q < RB; ++q) {
            float v = bv[q]; int i = bi[q];
#pragma unroll
            for (int o = 1; o < 64; o <<= 1) {
                float ov = __shfl_xor(v, o); int oi = __shfl_xor(i, o);
                if (ov < v || (ov == v && oi < i)) { v = ov; i = oi; }
            }
            if (lane == 0) { rv_s[q][w] = v; ri_s[q][w] = i; }
        }
        __syncthreads();
        if (tid < RB) {
            int tk = toks[tid];
            if (tk >= 0) {
                float fv = rv_s[tid][0]; int fi = ri_s[tid][0];
#pragma unroll
                for (int ww = 1; ww < 4; ++ww) {
                    if (rv_s[tid][ww] < fv || (rv_s[tid][ww] == fv && ri_s[tid][ww] < fi)) {
                        fv = rv_s[tid][ww]; fi = ri_s[tid][ww];
                    }
                }
                out_idx[tk] = (float)fi;
            }
        }
    }
}

// ---------------------------------------------------------------------------
__global__ void k_gather(float* __restrict__ zq, const float* __restrict__ emb,
                         const float* __restrict__ out_idx, float* __restrict__ partial) {
    __shared__ float red[4];
    const int tid = threadIdx.x;
    const int t0 = blockIdx.x * 128;
    const int tl = tid >> 1, part = tid & 1;
    int widx = (int)out_idx[t0 + tl];
    widx = min(max(widx, 0), KK - 1);
    const float* erow = emb + (size_t)widx * DD;
    float* qrow = zq + (size_t)(t0 + tl) * DD;
    float lsum = 0.f;
#pragma unroll
    for (int k = 0; k < 32; ++k) {
        int f = part + 2 * k;
        float4 e  = *(const float4*)(erow + f * 4);
        float4 zv = *(const float4*)(qrow + f * 4);
        float dx = e.x - zv.x, dy = e.y - zv.y, dz = e.z - zv.z, dw = e.w - zv.w;
        lsum += dx * dx + dy * dy + dz * dz + dw * dw;
        *(float4*)(qrow + f * 4) = e;
    }
#pragma unroll
    for (int off = 32; off; off >>= 1) lsum += __shfl_down(lsum, off);
    if ((tid & 63) == 0) red[tid >> 6] = lsum;
    __syncthreads();
    if (tid == 0) partial[blockIdx.x] = red[0] + red[1] + red[2] + red[3];
}

// ---------------------------------------------------------------------------
__global__ void k_loss(const float* __restrict__ partial, float* __restrict__ out_loss) {
    __shared__ float red[4];
    int tid = threadIdx.x;
    float s = partial[tid];
#pragma unroll
    for (int off = 32; off; off >>= 1) s += __shfl_down(s, off);
    if ((tid & 63) == 0) red[tid >> 6] = s;
    __syncthreads();
    if (tid == 0)
        out_loss[0] = (red[0] + red[1] + red[2] + red[3]) * (1.25f / 8388608.0f);
}

// ---------------------------------------------------------------------------
extern "C" void kernel_launch(void* const* d_in, const int* in_sizes, int n_in,
                              void* d_out, int out_size, void* d_ws, size_t ws_size,
                              hipStream_t stream) {
    const float* x   = (const float*)d_in[0];
    const float* W   = (const float*)d_in[1];
    const float* b   = (const float*)d_in[2];
    const float* emb = (const float*)d_in[3];

    float* out   = (float*)d_out;
    float* quant = out;                          // holds z, then quant
    float* oidx  = out + (size_t)TT * DD;
    float* oloss = oidx + TT;

    float* wsf     = (float*)d_ws;
    float* ee      = wsf;                        // [0, 1024)
    float* partial = wsf + 1024;                 // [1024, 1280)
    short* pemb    = (short*)(wsf + 1280);       // 262144 bf16 = 131072 f
    int*   g_nf    = (int*)(wsf + 132352);       // 1 int
    int*   g_list  = (int*)(wsf + 132353);       // 32768 ints
    float4* embP4  = (float4*)(wsf + 165124);    // 65536 float4 = 1 MB (16B-aligned)

    k_ee      <<<KK / 256, 256, 0, stream>>>(emb, ee, g_nf);
    k_pack    <<<128,      256, 0, stream>>>(emb, pemb, embP4);
    k_proj    <<<TT / 64,  256, 0, stream>>>(x, W, b, quant);
    k_screen  <<<TT / 64,  256, 0, stream>>>(quant, pemb, ee, oidx);
    k_compact <<<TT / 256, 256, 0, stream>>>(oidx, g_nf, g_list);
    k_rescoreT<<<512,      256, 0, stream>>>(quant, embP4, ee, g_nf, g_list, oidx);
    k_gather  <<<TT / 128, 256, 0, stream>>>(quant, emb, oidx, partial);
    k_loss    <<<1,        256, 0, stream>>>(partial, oloss);
}

// Round 5
// 270.903 us; speedup vs baseline: 1.4899x; 1.2790x over previous
//
#include <hip/hip_runtime.h>
#include <hip/hip_bf16.h>

// x[32768,256] f32, W[256,256], b[256], emb[1024,256]
// d_out: quant[32768*256] | indices[32768] (as float) | loss[1]
//
// Pipeline:
//   k_ee      : ee[n] = sum emb[n]^2 (+ zeroes the compaction counter)
//   k_pack    : emb -> bf16 packed in MFMA-fragment order (for k_screen) AND
//               emb -> fp32 transposed embP4[k4][n] (bit-exact copy, for
//               k_rescoreT's coalesced per-code loads).
//   k_proj    : z = x @ W^T + b via 3-way-split bf16 MFMA (err ~3e-7)
//   k_screen  : bf16 MFMA distance screen -> idx (+4096 flag if top-2 gap
//               < B_S). Fold/argmin/flag logic is the EXACT round-3 code;
//               B fragments stream straight into registers (4-deep ring,
//               zero barriers in the main loop). Scores bit-identical.
//   k_compact : ballot+atomic compaction of flagged token ids (order
//               arbitrary; per-token result order-independent).
//   k_rescoreT: exact fp32 re-argmin over the worklist. Thread owns codes
//               n = p*256+tid (p=0..3); k4 OUTER loop with ping-pong
//               double-buffered e (global, coalesced) and zq (LDS
//               broadcast) registers -> 128 FMAs per 12 memory issues,
//               loads in flight across the whole FMA block. Per-(code,
//               token) chains (k4 ascending, x/y/z/w), zz shuffle, fold
//               order (p ascending, q), s = fma(-2,dot,fl(zz+ee)), and
//               lexicographic (v,i) reductions are copied verbatim from
//               the harness-proven k_rescore -> bit-identical results.
//   k_gather  : quant = emb[idx] (in-place over z), loss partials
//   k_loss    : 1.25 * sum / (T*D)
//
// Numerics: reference dist = fl(fl(zz+ee[n]) - 2*dot) quantized to ulp(~256)
// ~3e-5. Screen score error sigma ~2.7e-5; B_S = 5e-4 >> 8*sigma + 2 ulp, so
// unflagged tokens have a guaranteed-unique exact argmin; flagged tokens get
// the full exact scan — the round-2/3 validated formula.
#define TT 32768
#define DD 256
#define KK 1024
#define B_S 5e-4f

typedef __attribute__((ext_vector_type(8)))  short bf16x8;
typedef __attribute__((ext_vector_type(4)))  short bf16x4s;
typedef __attribute__((ext_vector_type(16))) float f32x16;

static inline __device__ short f2bf(float v) {
    __hip_bfloat16 h = __float2bfloat16(v);
    return __builtin_bit_cast(short, h);
}
static inline __device__ float bf2f(short s) {
    __hip_bfloat16 h = __builtin_bit_cast(__hip_bfloat16, s);
    return __bfloat162float(h);
}

// ---------------------------------------------------------------------------
__global__ void k_ee(const float* __restrict__ emb, float* __restrict__ ee,
                     int* __restrict__ g_nf) {
    if (blockIdx.x == 0 && threadIdx.x == 0) g_nf[0] = 0;
    int n = blockIdx.x * 256 + threadIdx.x;
    if (n >= KK) return;
    const float4* r = (const float4*)(emb + (size_t)n * DD);
    float s = 0.f;
#pragma unroll
    for (int i = 0; i < DD / 4; ++i) {
        float4 v = r[i];
        s += v.x * v.x + v.y * v.y + v.z * v.z + v.w * v.w;
    }
    ee[n] = s;
}

// ---------------------------------------------------------------------------
// Pack emb as bf16 in MFMA-fragment order (pemb) and as fp32 transposed
// float4 blocks (embP4[k4*1024 + n] = emb[n][k4*4 .. +3], bit-exact).
__global__ void k_pack(const float* __restrict__ emb, short* __restrict__ pemb,
                       float4* __restrict__ embP4) {
    int u = blockIdx.x * 256 + threadIdx.x;
    int lane = u & 63;
    int ks  = (u >> 6) & 1, nb = (u >> 7) & 3;
    int kbi = (u >> 9) & 7, nc = (u >> 12) & 7;
    int n = nc * 128 + nb * 32 + (lane & 31);
    int k = kbi * 32 + ks * 16 + (lane >> 5) * 8;
    const float* src = emb + (size_t)n * DD + k;
    float4 v0 = *(const float4*)(src);
    float4 v1 = *(const float4*)(src + 4);
    bf16x8 hb = { f2bf(v0.x), f2bf(v0.y), f2bf(v0.z), f2bf(v0.w),
                  f2bf(v1.x), f2bf(v1.y), f2bf(v1.z), f2bf(v1.w) };
    *(bf16x8*)(pemb + (size_t)u * 8) = hb;
    embP4[(size_t)(k >> 2) * KK + n]       = v0;
    embP4[(size_t)((k >> 2) + 1) * KK + n] = v1;
}

// ---------------------------------------------------------------------------
// z = x @ W^T + b via 3-way split bf16 MFMA. 64 tokens x 256 outs per block.
#define PW 40   // bf16 row stride for 32-k tiles (80 B: 16B-aligned)

__launch_bounds__(256, 2)
__global__ void k_proj(const float* __restrict__ x, const float* __restrict__ W,
                       const float* __restrict__ bias, float* __restrict__ z) {
    __shared__ __align__(16) short Ax[3][64 * PW];    // 15 KB
    __shared__ __align__(16) short Bw[3][256 * PW];   // 60 KB
    const int tid = threadIdx.x;
    const int w = tid >> 6, lane = tid & 63;
    const int l31 = lane & 31, h = lane >> 5;
    const int t0 = blockIdx.x * 64;
    const int wt = (w & 1) * 32;        // wave token offset
    const int wc = (w >> 1) * 128;      // wave col offset

    f32x16 acc[4];
#pragma unroll
    for (int cb = 0; cb < 4; ++cb)
#pragma unroll
        for (int r = 0; r < 16; ++r) acc[cb][r] = 0.f;

    for (int kb = 0; kb < DD; kb += 32) {
        __syncthreads();
        // x tile 64x32 -> 3-way split
#pragma unroll
        for (int j = 0; j < 2; ++j) {
            int idx = j * 256 + tid, row = idx >> 3, c4 = idx & 7;
            float4 v = *(const float4*)(x + (size_t)(t0 + row) * DD + kb + c4 * 4);
            float e[4] = {v.x, v.y, v.z, v.w};
            bf16x4s s1, s2, s3;
#pragma unroll
            for (int q = 0; q < 4; ++q) {
                short h1 = f2bf(e[q]); float r1 = e[q] - bf2f(h1);
                short h2 = f2bf(r1);   float r2 = r1 - bf2f(h2);
                short h3 = f2bf(r2);
                s1[q] = h1; s2[q] = h2; s3[q] = h3;
            }
            int a = row * PW + c4 * 4;
            *(bf16x4s*)&Ax[0][a] = s1; *(bf16x4s*)&Ax[1][a] = s2; *(bf16x4s*)&Ax[2][a] = s3;
        }
        // W tile 256x32 -> 3-way split
#pragma unroll
        for (int j = 0; j < 8; ++j) {
            int idx = j * 256 + tid, row = idx >> 3, c4 = idx & 7;
            float4 v = *(const float4*)(W + (size_t)row * DD + kb + c4 * 4);
            float e[4] = {v.x, v.y, v.z, v.w};
            bf16x4s s1, s2, s3;
#pragma unroll
            for (int q = 0; q < 4; ++q) {
                short h1 = f2bf(e[q]); float r1 = e[q] - bf2f(h1);
                short h2 = f2bf(r1);   float r2 = r1 - bf2f(h2);
                short h3 = f2bf(r2);
                s1[q] = h1; s2[q] = h2; s3[q] = h3;
            }
            int a = row * PW + c4 * 4;
            *(bf16x4s*)&Bw[0][a] = s1; *(bf16x4s*)&Bw[1][a] = s2; *(bf16x4s*)&Bw[2][a] = s3;
        }
        __syncthreads();
#pragma unroll
        for (int ks = 0; ks < 2; ++ks) {
            int ao = (wt + l31) * PW + ks * 16 + h * 8;
            bf16x8 a1 = *(bf16x8*)&Ax[0][ao];
            bf16x8 a2 = *(bf16x8*)&Ax[1][ao];
            bf16x8 a3 = *(bf16x8*)&Ax[2][ao];
#pragma unroll
            for (int cb = 0; cb < 4; ++cb) {
                int bo = (wc + cb * 32 + l31) * PW + ks * 16 + h * 8;
                bf16x8 b1 = *(bf16x8*)&Bw[0][bo];
                bf16x8 b2 = *(bf16x8*)&Bw[1][bo];
                bf16x8 b3 = *(bf16x8*)&Bw[2][bo];
                // small terms first for accumulation accuracy
                acc[cb] = __builtin_amdgcn_mfma_f32_32x32x16_bf16(a1, b3, acc[cb], 0, 0, 0);
                acc[cb] = __builtin_amdgcn_mfma_f32_32x32x16_bf16(a2, b2, acc[cb], 0, 0, 0);
                acc[cb] = __builtin_amdgcn_mfma_f32_32x32x16_bf16(a3, b1, acc[cb], 0, 0, 0);
                acc[cb] = __builtin_amdgcn_mfma_f32_32x32x16_bf16(a1, b2, acc[cb], 0, 0, 0);
                acc[cb] = __builtin_amdgcn_mfma_f32_32x32x16_bf16(a2, b1, acc[cb], 0, 0, 0);
                acc[cb] = __builtin_amdgcn_mfma_f32_32x32x16_bf16(a1, b1, acc[cb], 0, 0, 0);
            }
        }
    }
    // epilogue: C/D layout col=lane&31, row=(r&3)+8*(r>>2)+4*(lane>>5)
#pragma unroll
    for (int cb = 0; cb < 4; ++cb) {
        int col = wc + cb * 32 + l31;
        float bc = bias[col];
#pragma unroll
        for (int r = 0; r < 16; ++r) {
            int row = (r & 3) + 8 * (r >> 2) + 4 * h;
            z[(size_t)(t0 + wt + row) * DD + col] = acc[cb][r] + bc;
        }
    }
}

// ---------------------------------------------------------------------------
// bf16 MFMA screening. Fold/argmin/flag = EXACT round-3 code. B fragments
// loaded straight into registers from the prepacked buffer: 4-deep ring,
// perfectly coalesced 16B/lane loads, ZERO barriers in the main loop
// (A_s is read-only after the single init barrier). Same MFMA values and
// per-accumulator order as the validated kernel -> bit-identical scores.
#define SW 264   // A_s row stride (bf16 elems)

__launch_bounds__(256, 2)
__global__ void k_screen(const float* __restrict__ z, const short* __restrict__ pemb,
                         const float* __restrict__ ee_g, float* __restrict__ out_idx) {
    __shared__ __align__(16) short A_s[64 * SW];       // 33 KB
    __shared__ float ee_s[1024];
    __shared__ float zzs[64];
    __shared__ float r_bv[64]; __shared__ int r_bi[64]; __shared__ float r_sv[64];

    const int tid = threadIdx.x;
    const int w = tid >> 6, lane = tid & 63;
    const int l31 = lane & 31, h = lane >> 5;
    const int t0 = blockIdx.x * 64;
    const int wr = (w >> 1) * 32, wc = (w & 1) * 64;

#pragma unroll
    for (int i = 0; i < 4; ++i) ee_s[i * 256 + tid] = ee_g[i * 256 + tid];

    // A init: z tile -> bf16 LDS (full K=256 resident) + exact fp32 zz sums
#pragma unroll
    for (int i = 0; i < 16; ++i) {
        int tl = i * 4 + w;
        float4 v = *(const float4*)(z + (size_t)(t0 + tl) * DD + lane * 4);
        float sq = v.x * v.x + v.y * v.y + v.z * v.z + v.w * v.w;
#pragma unroll
        for (int o = 32; o; o >>= 1) sq += __shfl_xor(sq, o);
        if (lane == 0) zzs[tl] = sq;
        bf16x4s hb = {f2bf(v.x), f2bf(v.y), f2bf(v.z), f2bf(v.w)};
        *(bf16x4s*)&A_s[tl * SW + lane * 4] = hb;
    }
    __syncthreads();   // A_s, zzs, ee_s ready — the ONLY barrier before epilogue

    // per-wave B fragment units within a tile (16B unit = chunk*64 + lane)
    const int u00 = ((((w & 1) * 2 + 0) * 2 + 0) * 64 + lane) * 8;  // b0 ks0
    const int u01 = ((((w & 1) * 2 + 0) * 2 + 1) * 64 + lane) * 8;  // b0 ks1
    const int u10 = ((((w & 1) * 2 + 1) * 2 + 0) * 64 + lane) * 8;  // b1 ks0
    const int u11 = ((((w & 1) * 2 + 1) * 2 + 1) * 64 + lane) * 8;  // b1 ks1

    // 4-deep register ring of B fragments
    bf16x8 B00[4], B01[4], B10[4], B11[4];
#pragma unroll
    for (int s = 0; s < 4; ++s) {
        const short* gt = pemb + (size_t)s * 4096;
        B00[s] = *(const bf16x8*)(gt + u00);
        B01[s] = *(const bf16x8*)(gt + u01);
        B10[s] = *(const bf16x8*)(gt + u10);
        B11[s] = *(const bf16x8*)(gt + u11);
    }

    float bestv[16], secv[16]; int besti[16];
#pragma unroll
    for (int r = 0; r < 16; ++r) { bestv[r] = 1e30f; secv[r] = 1e30f; besti[r] = 0; }

    f32x16 acc0, acc1;
    for (int tq = 0; tq < 16; ++tq) {
#pragma unroll
        for (int s = 0; s < 4; ++s) {
            const int t = tq * 4 + s;
            const int nc = t >> 3, kbi = t & 7;
            if (kbi == 0) {
#pragma unroll
                for (int r = 0; r < 16; ++r) { acc0[r] = 0.f; acc1[r] = 0.f; }
            }
            // A fragments for this (kbi); ks0 then ks1 per acc (validated order)
            bf16x8 a0 = *(bf16x8*)&A_s[(wr + l31) * SW + kbi * 32 + 0 * 16 + h * 8];
            bf16x8 a1 = *(bf16x8*)&A_s[(wr + l31) * SW + kbi * 32 + 1 * 16 + h * 8];
            acc0 = __builtin_amdgcn_mfma_f32_32x32x16_bf16(a0, B00[s], acc0, 0, 0, 0);
            acc1 = __builtin_amdgcn_mfma_f32_32x32x16_bf16(a0, B10[s], acc1, 0, 0, 0);
            acc0 = __builtin_amdgcn_mfma_f32_32x32x16_bf16(a1, B01[s], acc0, 0, 0, 0);
            acc1 = __builtin_amdgcn_mfma_f32_32x32x16_bf16(a1, B11[s], acc1, 0, 0, 0);
            // refill this slot with tile t+4 (clamped; tail reloads are unused)
            {
                const int tn = (t + 4 > 63) ? 63 : t + 4;
                const short* gt = pemb + (size_t)tn * 4096;
                B00[s] = *(const bf16x8*)(gt + u00);
                B01[s] = *(const bf16x8*)(gt + u01);
                B10[s] = *(const bf16x8*)(gt + u10);
                B11[s] = *(const bf16x8*)(gt + u11);
            }
            // fold: s = fl(fl(zz+ee) - 2*dot), track top-2 values + best index
            if (kbi == 7) {
#pragma unroll
                for (int j = 0; j < 2; ++j) {
                    int n = nc * 128 + wc + j * 32 + l31;
                    float en = ee_s[n];
#pragma unroll
                    for (int r = 0; r < 16; ++r) {
                        int row = (r & 3) + 8 * (r >> 2) + 4 * h;
                        float u = zzs[wr + row] + en;
                        float d = (j == 0) ? acc0[r] : acc1[r];
                        float sc = fmaf(-2.f, d, u);
                        if (sc < bestv[r])      { secv[r] = bestv[r]; bestv[r] = sc; besti[r] = n; }
                        else if (sc < secv[r])  { secv[r] = sc; }
                    }
                }
            }
        }
    }

    // cross-lane reduce within each 32-lane half (cols)
#pragma unroll
    for (int o = 1; o < 32; o <<= 1) {
#pragma unroll
        for (int r = 0; r < 16; ++r) {
            float ov = __shfl_xor(bestv[r], o);
            int   oi = __shfl_xor(besti[r], o);
            float os = __shfl_xor(secv[r], o);
            float mx = fmaxf(bestv[r], ov);
            secv[r] = fminf(fminf(secv[r], os), mx);
            if (ov < bestv[r] || (ov == bestv[r] && oi < besti[r])) { bestv[r] = ov; besti[r] = oi; }
        }
    }
    // combine the two col-parity waves per row block via LDS
    if ((w & 1) == 0 && l31 == 0) {
#pragma unroll
        for (int r = 0; r < 16; ++r) {
            int tr = wr + (r & 3) + 8 * (r >> 2) + 4 * h;
            r_bv[tr] = bestv[r]; r_bi[tr] = besti[r]; r_sv[tr] = secv[r];
        }
    }
    __syncthreads();
    if ((w & 1) == 1 && l31 == 0) {
#pragma unroll
        for (int r = 0; r < 16; ++r) {
            int tr = wr + (r & 3) + 8 * (r >> 2) + 4 * h;
            float lv = r_bv[tr]; int li = r_bi[tr]; float ls = r_sv[tr];
            float mx = fmaxf(lv, bestv[r]);
            float ns = fminf(fminf(ls, secv[r]), mx);
            float nv; int ni;
            if (bestv[r] < lv || (bestv[r] == lv && besti[r] < li)) { nv = bestv[r]; ni = besti[r]; }
            else { nv = lv; ni = li; }
            r_bv[tr] = nv; r_bi[tr] = ni; r_sv[tr] = ns;
        }
    }
    __syncthreads();
    if (tid < 64) {
        float bv = r_bv[tid], sv = r_sv[tid];
        int bi = r_bi[tid];
        float flag = ((sv - bv) < B_S) ? 4096.0f : 0.0f;
        out_idx[t0 + tid] = (float)bi + flag;
    }
}

// ---------------------------------------------------------------------------
// Compact flagged token ids into a global worklist (order-independent result).
__global__ void k_compact(const float* __restrict__ out_idx, int* __restrict__ g_nf,
                          int* __restrict__ g_list) {
    __shared__ int wbase[4];
    __shared__ int bbase;
    const int tid = threadIdx.x;
    const int t = blockIdx.x * 256 + tid;
    const int wid = tid >> 6, lane = tid & 63;
    bool fl = out_idx[t] >= 4096.0f;
    unsigned long long m = __ballot(fl);
    if (lane == 0) wbase[wid] = __popcll(m);
    __syncthreads();
    if (tid == 0) {
        int s = 0;
#pragma unroll
        for (int i = 0; i < 4; ++i) { int c = wbase[i]; wbase[i] = s; s += c; }
        bbase = atomicAdd(g_nf, s);
    }
    __syncthreads();
    if (fl) {
        int rank = __popcll(m & ((1ull << lane) - 1ull));
        g_list[bbase + wbase[wid] + rank] = t;
    }
}

// ---------------------------------------------------------------------------
// Exact fp32 re-argmin over the worklist, 8 tokens/batch, grid-stride.
// Thread owns codes n = p*256 + tid (p = 0..3). k4 is the OUTER loop:
// per k4 we read the 8 zq broadcasts once (feeding all 4 p's = 128 FMAs)
// and ping-pong double-buffer both the coalesced embP4 loads and the zq
// LDS reads, so the next iteration's memory is in flight under the current
// FMA block. Per-(code,token) chains (k4 ascending, x/y/z/w), zz shuffle,
// fold (p ascending, then q), and all reductions are copied verbatim from
// the harness-proven k_rescore -> bit-identical results.
#define RB 8    // tokens per batch (validated batch size)

__launch_bounds__(256, 2)
__global__ void k_rescoreT(const float* __restrict__ z, const float4* __restrict__ embP4,
                           const float* __restrict__ ee_g, const int* __restrict__ g_nf,
                           const int* __restrict__ g_list, float* __restrict__ out_idx) {
    __shared__ float zrows[RB][256];                 // 8 KB
    __shared__ float zz8[RB];
    __shared__ int   toks[RB];
    __shared__ float rv_s[RB][4]; __shared__ int ri_s[RB][4];
    const int tid = threadIdx.x;
    const int w = tid >> 6, lane = tid & 63;
    const int nf = g_nf[0];

    for (int base = blockIdx.x * RB; base < nf; base += gridDim.x * RB) {
        __syncthreads();   // previous batch fully done (zrows/toks reuse)
        if (tid < RB) toks[tid] = (base + tid < nf) ? g_list[base + tid] : -1;
        __syncthreads();
        // stage z rows (pad slots -> zeros: no stale-LDS reads)
#pragma unroll
        for (int qq = 0; qq < RB; ++qq) {
            int tok = toks[qq];
            zrows[qq][tid] = (tok >= 0) ? z[(size_t)tok * DD + tid] : 0.f;
        }
        __syncthreads();
        // zz — EXACT validated per-row arithmetic (wave w rows w, w+4)
        for (int qq = w; qq < RB; qq += 4) {
            float s = 0.f;
#pragma unroll
            for (int k = 0; k < 4; ++k) { float vv = zrows[qq][lane + 64 * k]; s += vv * vv; }
#pragma unroll
            for (int o = 32; o; o >>= 1) s += __shfl_xor(s, o);
            if (lane == 0) zz8[qq] = s;
        }
        __syncthreads();   // zz8 ready

        // hoisted ee for this thread's 4 codes (same loaded values as before)
        float en4[4];
#pragma unroll
        for (int p = 0; p < 4; ++p) en4[p] = ee_g[p * 256 + tid];

        float d[4][RB];
#pragma unroll
        for (int p = 0; p < 4; ++p)
#pragma unroll
            for (int q = 0; q < RB; ++q) d[p][q] = 0.f;

        // ping-pong buffers: eX = 4 coalesced global float4, zX = 8 LDS bcast
        float4 eA[4], eB[4], zA[RB], zB[RB];
#pragma unroll
        for (int p = 0; p < 4; ++p) eA[p] = embP4[(size_t)0 * KK + p * 256 + tid];
#pragma unroll
        for (int q = 0; q < RB; ++q) zA[q] = *(const float4*)&zrows[q][0];

        for (int k4 = 0; k4 < 64; k4 += 2) {
            // issue k4+1 into B (always valid: k4+1 <= 63)
#pragma unroll
            for (int p = 0; p < 4; ++p) eB[p] = embP4[(size_t)(k4 + 1) * KK + p * 256 + tid];
#pragma unroll
            for (int q = 0; q < RB; ++q) zB[q] = *(const float4*)&zrows[q][(k4 + 1) * 4];
            // compute k4 with A — EXACT chains: k4 ascending, x/y/z/w
#pragma unroll
            for (int p = 0; p < 4; ++p)
#pragma unroll
                for (int q = 0; q < RB; ++q) {
                    d[p][q] = fmaf(eA[p].x, zA[q].x, d[p][q]);
                    d[p][q] = fmaf(eA[p].y, zA[q].y, d[p][q]);
                    d[p][q] = fmaf(eA[p].z, zA[q].z, d[p][q]);
                    d[p][q] = fmaf(eA[p].w, zA[q].w, d[p][q]);
                }
            // issue k4+2 into A (guarded)
            if (k4 < 62) {
#pragma unroll
                for (int p = 0; p < 4; ++p) eA[p] = embP4[(size_t)(k4 + 2) * KK + p * 256 + tid];
#pragma unroll
                for (int q = 0; q < RB; ++q) zA[q] = *(const float4*)&zrows[q][(k4 + 2) * 4];
            }
            // compute k4+1 with B
#pragma unroll
            for (int p = 0; p < 4; ++p)
#pragma unroll
                for (int q = 0; q < RB; ++q) {
                    d[p][q] = fmaf(eB[p].x, zB[q].x, d[p][q]);
                    d[p][q] = fmaf(eB[p].y, zB[q].y, d[p][q]);
                    d[p][q] = fmaf(eB[p].z, zB[q].z, d[p][q]);
                    d[p][q] = fmaf(eB[p].w, zB[q].w, d[p][q]);
                }
        }

        // fold: p ascending (= n ascending per thread), then q — verbatim
        float bv[RB]; int bi[RB];
#pragma unroll
        for (int q = 0; q < RB; ++q) { bv[q] = 1e30f; bi[q] = 0; }
#pragma unroll
        for (int p = 0; p < 4; ++p) {
            const int n = p * 256 + tid;
#pragma unroll
            for (int q = 0; q < RB; ++q) {
                float u = zz8[q] + en4[p];         // fl(zz+ee[n])
                float s = fmaf(-2.f, d[p][q], u);  // fl(u - 2*dot)
                if (s < bv[q]) { bv[q] = s; bi[q] = n; }
            }
        }
        // per-token block reduce: lexicographic (value, index) first-min
        for (int q = 0; q < RB; ++q) {
            float v = bv[q]; int i = bi[q];
#pragma unroll
            for (int o = 1; o < 64; o <<= 1) {
                float ov = __shfl_xor(v, o); int oi = __shfl_xor(i, o);
                if (ov < v || (ov == v && oi < i)) { v = ov; i = oi; }
            }
            if (lane == 0) { rv_s[q][w] = v; ri_s[q][w] = i; }
        }
        __syncthreads();
        if (tid < RB) {
            int tk = toks[tid];
            if (tk >= 0) {
                float fv = rv_s[tid][0]; int fi = ri_s[tid][0];
#pragma unroll
                for (int ww = 1; ww < 4; ++ww) {
                    if (rv_s[tid][ww] < fv || (rv_s[tid][ww] == fv && ri_s[tid][ww] < fi)) {
                        fv = rv_s[tid][ww]; fi = ri_s[tid][ww];
                    }
                }
                out_idx[tk] = (float)fi;
            }
        }
    }
}

// ---------------------------------------------------------------------------
__global__ void k_gather(float* __restrict__ zq, const float* __restrict__ emb,
                         const float* __restrict__ out_idx, float* __restrict__ partial) {
    __shared__ float red[4];
    const int tid = threadIdx.x;
    const int t0 = blockIdx.x * 128;
    const int tl = tid >> 1, part = tid & 1;
    int widx = (int)out_idx[t0 + tl];
    widx = min(max(widx, 0), KK - 1);
    const float* erow = emb + (size_t)widx * DD;
    float* qrow = zq + (size_t)(t0 + tl) * DD;
    float lsum = 0.f;
#pragma unroll
    for (int k = 0; k < 32; ++k) {
        int f = part + 2 * k;
        float4 e  = *(const float4*)(erow + f * 4);
        float4 zv = *(const float4*)(qrow + f * 4);
        float dx = e.x - zv.x, dy = e.y - zv.y, dz = e.z - zv.z, dw = e.w - zv.w;
        lsum += dx * dx + dy * dy + dz * dz + dw * dw;
        *(float4*)(qrow + f * 4) = e;
    }
#pragma unroll
    for (int off = 32; off; off >>= 1) lsum += __shfl_down(lsum, off);
    if ((tid & 63) == 0) red[tid >> 6] = lsum;
    __syncthreads();
    if (tid == 0) partial[blockIdx.x] = red[0] + red[1] + red[2] + red[3];
}

// ---------------------------------------------------------------------------
__global__ void k_loss(const float* __restrict__ partial, float* __restrict__ out_loss) {
    __shared__ float red[4];
    int tid = threadIdx.x;
    float s = partial[tid];
#pragma unroll
    for (int off = 32; off; off >>= 1) s += __shfl_down(s, off);
    if ((tid & 63) == 0) red[tid >> 6] = s;
    __syncthreads();
    if (tid == 0)
        out_loss[0] = (red[0] + red[1] + red[2] + red[3]) * (1.25f / 8388608.0f);
}

// ---------------------------------------------------------------------------
extern "C" void kernel_launch(void* const* d_in, const int* in_sizes, int n_in,
                              void* d_out, int out_size, void* d_ws, size_t ws_size,
                              hipStream_t stream) {
    const float* x   = (const float*)d_in[0];
    const float* W   = (const float*)d_in[1];
    const float* b   = (const float*)d_in[2];
    const float* emb = (const float*)d_in[3];

    float* out   = (float*)d_out;
    float* quant = out;                          // holds z, then quant
    float* oidx  = out + (size_t)TT * DD;
    float* oloss = oidx + TT;

    float* wsf     = (float*)d_ws;
    float* ee      = wsf;                        // [0, 1024)
    float* partial = wsf + 1024;                 // [1024, 1280)
    short* pemb    = (short*)(wsf + 1280);       // 262144 bf16 = 131072 f
    int*   g_nf    = (int*)(wsf + 132352);       // 1 int
    int*   g_list  = (int*)(wsf + 132353);       // 32768 ints
    float4* embP4  = (float4*)(wsf + 165124);    // 65536 float4 = 1 MB (16B-aligned)

    k_ee      <<<KK / 256, 256, 0, stream>>>(emb, ee, g_nf);
    k_pack    <<<128,      256, 0, stream>>>(emb, pemb, embP4);
    k_proj    <<<TT / 64,  256, 0, stream>>>(x, W, b, quant);
    k_screen  <<<TT / 64,  256, 0, stream>>>(quant, pemb, ee, oidx);
    k_compact <<<TT / 256, 256, 0, stream>>>(oidx, g_nf, g_list);
    k_rescoreT<<<512,      256, 0, stream>>>(quant, embP4, ee, g_nf, g_list, oidx);
    k_gather  <<<TT / 128, 256, 0, stream>>>(quant, emb, oidx, partial);
    k_loss    <<<1,        256, 0, stream>>>(partial, oloss);
}